// Round 1
// baseline (10382.056 us; speedup 1.0000x reference)
//
#include <hip/hip_runtime.h>
#include <math.h>

#define N_NODES 100000
#define H 200
#define R2 500
#define T_STEPS 3
#define E_EDGES 300000
#define R2E 400000
#define SE_EDGES 4000
#define SR 8
#define S2E 8000
#define SLOPE 0.22916666666666666f

static __device__ __forceinline__ float sigf(float x) { return 1.f / (1.f + expf(-x)); }

// ---------------- l2 normalize rows (src may alias dst) ----------------
__global__ __launch_bounds__(256) void l2norm_k(const float* __restrict__ src,
                                                float* __restrict__ dst, int rows) {
    int r = blockIdx.x;
    if (r >= rows) return;
    int t = threadIdx.x;
    float v = (t < H) ? src[(size_t)r * H + t] : 0.f;
    float s = v * v;
    for (int o = 32; o > 0; o >>= 1) s += __shfl_down(s, o);
    __shared__ float red[4];
    if ((t & 63) == 0) red[t >> 6] = s;
    __syncthreads();
    if (t == 0) red[0] = 1.f / fmaxf(sqrtf(red[0] + red[1] + red[2] + red[3]), 1e-12f);
    __syncthreads();
    if (t < H) dst[(size_t)r * H + t] = v * red[0];
}

// ---------------- generic counting (indeg / CSR counts) ----------------
__global__ void cnt_k(const int* __restrict__ d, int n, int* __restrict__ cnt) {
    int i = blockIdx.x * blockDim.x + threadIdx.x;
    if (i < n) atomicAdd(&cnt[d[i]], 1);
}

// ---------------- segment counts with LDS hierarchy ----------------
__global__ __launch_bounds__(256) void seg_cnt_k(const int* __restrict__ seg, int n,
                                                 int* __restrict__ cnt, int nseg) {
    __shared__ int lc[500];
    for (int i = threadIdx.x; i < nseg; i += 256) lc[i] = 0;
    __syncthreads();
    int chunk = (n + gridDim.x - 1) / gridDim.x;
    int beg = blockIdx.x * chunk;
    int end = beg + chunk; if (end > n) end = n;
    for (int i = beg + threadIdx.x; i < end; i += 256) atomicAdd(&lc[seg[i]], 1);
    __syncthreads();
    for (int i = threadIdx.x; i < nseg; i += 256) if (lc[i]) atomicAdd(&cnt[i], lc[i]);
}

// ---------------- segment sum of gathered rows, LDS col-chunked ----------------
#define SEG_CW 25
__global__ __launch_bounds__(256) void seg_acc_k(const float* __restrict__ hsrc,
                                                 const int* __restrict__ idx,
                                                 const int* __restrict__ seg, int n,
                                                 float* __restrict__ acc, int nseg) {
    __shared__ float lacc[500 * SEG_CW];  // 50 KB
    int cg = blockIdx.x & 7;              // 8 column groups of 25
    int pb = blockIdx.x >> 3;
    int NPB = gridDim.x >> 3;
    int t = threadIdx.x;
    for (int i = t; i < nseg * SEG_CW; i += 256) lacc[i] = 0.f;
    __syncthreads();
    int chunk = (n + NPB - 1) / NPB;
    int beg = pb * chunk;
    int end = beg + chunk; if (end > n) end = n;
    if (t < 250) {
        int il = t / SEG_CW;        // 0..9
        int c = t - il * SEG_CW;    // 0..24
        int col = cg * SEG_CW + c;
        for (int i = beg + il; i < end; i += 10) {
            int r = seg[i];
            int e = idx[i];
            atomicAdd(&lacc[r * SEG_CW + c], hsrc[(size_t)e * H + col]);
        }
    }
    __syncthreads();
    for (int i = t; i < nseg * SEG_CW; i += 256) {
        int r = i / SEG_CW, c = i - (i / SEG_CW) * SEG_CW;
        atomicAdd(&acc[(size_t)r * H + cg * SEG_CW + c], lacc[i]);
    }
}

__global__ void seg_div_k(float* __restrict__ acc, const int* __restrict__ cnt, int rows) {
    int i = blockIdx.x * blockDim.x + threadIdx.x;
    if (i < rows * H) {
        int c = cnt[i / H];
        acc[i] /= (float)(c > 0 ? c : 1);
    }
}

// ---------------- fused LSTM cell + l2norm of h and c ----------------
__global__ __launch_bounds__(256) void lstm_k(const float* __restrict__ x1, const float* __restrict__ x2,
                                              const float* __restrict__ hprev, const float* __restrict__ cprev,
                                              const float* __restrict__ Wih, const float* __restrict__ Whh,
                                              const float* __restrict__ bih, const float* __restrict__ bhh,
                                              float* __restrict__ hout, float* __restrict__ cout, int rows) {
    int r = blockIdx.x;
    if (r >= rows) return;
    __shared__ float xb[2 * H], hb[H], gb[4 * H], hv[H], cv[H];
    __shared__ float red[8];
    int t = threadIdx.x;
    for (int i = t; i < 2 * H; i += 256)
        xb[i] = (i < H) ? x1[(size_t)r * H + i] : x2[(size_t)r * H + i - H];
    if (t < H) hb[t] = hprev[(size_t)r * H + t];
    __syncthreads();
    for (int j = t; j < 4 * H; j += 256) {
        float s = bih[j] + bhh[j];
        const float* wi = Wih + (size_t)j * 2 * H;
        for (int k = 0; k < 2 * H; ++k) s += xb[k] * wi[k];
        const float* wh = Whh + (size_t)j * H;
        for (int k = 0; k < H; ++k) s += hb[k] * wh[k];
        gb[j] = s;
    }
    __syncthreads();
    if (t < H) {
        float ig = sigf(gb[t]);
        float fg = sigf(gb[H + t]);
        float gg = tanhf(gb[2 * H + t]);
        float og = sigf(gb[3 * H + t]);
        float c2 = fg * cprev[(size_t)r * H + t] + ig * gg;
        cv[t] = c2;
        hv[t] = og * tanhf(c2);
    }
    __syncthreads();
    float sh = 0.f, sc = 0.f;
    if (t < H) { sh = hv[t] * hv[t]; sc = cv[t] * cv[t]; }
    for (int o = 32; o > 0; o >>= 1) { sh += __shfl_down(sh, o); sc += __shfl_down(sc, o); }
    if ((t & 63) == 0) { red[t >> 6] = sh; red[4 + (t >> 6)] = sc; }
    __syncthreads();
    if (t == 0) {
        red[0] = 1.f / fmaxf(sqrtf(red[0] + red[1] + red[2] + red[3]), 1e-12f);
        red[4] = 1.f / fmaxf(sqrtf(red[4] + red[5] + red[6] + red[7]), 1e-12f);
    }
    __syncthreads();
    if (t < H) {
        hout[(size_t)r * H + t] = hv[t] * red[0];
        cout[(size_t)r * H + t] = cv[t] * red[4];
    }
}

// ---------------- fused small GRU + l2norm ----------------
__global__ __launch_bounds__(256) void gru_small_k(const float* __restrict__ x, const float* __restrict__ h,
                                                   const float* __restrict__ Wih, const float* __restrict__ Whh,
                                                   const float* __restrict__ bih, const float* __restrict__ bhh,
                                                   float* __restrict__ outp, int rows) {
    int r = blockIdx.x;
    if (r >= rows) return;
    __shared__ float xb[H], hb[H], gi[3 * H], gh[3 * H], ov[H];
    __shared__ float red[4];
    int t = threadIdx.x;
    if (t < H) { xb[t] = x[(size_t)r * H + t]; hb[t] = h[(size_t)r * H + t]; }
    __syncthreads();
    for (int j = t; j < 3 * H; j += 256) {
        float si = bih[j], sh2 = bhh[j];
        const float* wi = Wih + (size_t)j * H;
        const float* wh = Whh + (size_t)j * H;
        for (int k = 0; k < H; ++k) { si += xb[k] * wi[k]; sh2 += hb[k] * wh[k]; }
        gi[j] = si; gh[j] = sh2;
    }
    __syncthreads();
    if (t < H) {
        float rr = sigf(gi[t] + gh[t]);
        float zz = sigf(gi[H + t] + gh[H + t]);
        float nn = tanhf(gi[2 * H + t] + rr * gh[2 * H + t]);
        ov[t] = (1.f - zz) * nn + zz * hb[t];
    }
    __syncthreads();
    float s = (t < H) ? ov[t] * ov[t] : 0.f;
    for (int o = 32; o > 0; o >>= 1) s += __shfl_down(s, o);
    if ((t & 63) == 0) red[t >> 6] = s;
    __syncthreads();
    if (t == 0) red[0] = 1.f / fmaxf(sqrtf(red[0] + red[1] + red[2] + red[3]), 1e-12f);
    __syncthreads();
    if (t < H) outp[(size_t)r * H + t] = ov[t] * red[0];
}

// ---------------- super-graph raw message aggregation ----------------
__global__ __launch_bounds__(256) void sup_agg_k(const float* __restrict__ cur, const float* __restrict__ prel,
                                                 const int* __restrict__ ss, const int* __restrict__ sd,
                                                 const int* __restrict__ se, float* __restrict__ sagg, int nE) {
    int e = blockIdx.x;
    if (e >= nE) return;
    int t = threadIdx.x;
    if (t < H) {
        int s = ss[e], d = sd[e], et = se[e];
        float v = cur[(size_t)s * H + t] + prel[(size_t)et * H + t];
        atomicAdd(&sagg[(size_t)d * H + t], v);
    }
}

// ---------------- super-graph combine: rrelu(agg@Wn + cur@Wsel) ----------------
__global__ __launch_bounds__(256) void sup_comb_k(const float* __restrict__ agg, const float* __restrict__ cur,
                                                  const float* __restrict__ Wn, const float* __restrict__ We,
                                                  const float* __restrict__ Wl, const int* __restrict__ indeg,
                                                  float* __restrict__ outp) {
    int r = blockIdx.x;
    __shared__ float ar[H], cr[H];
    int t = threadIdx.x;
    if (t < H) { ar[t] = agg[(size_t)r * H + t]; cr[t] = cur[(size_t)r * H + t]; }
    __syncthreads();
    const float* W2 = (indeg[r] > 0) ? We : Wl;
    if (t < H) {
        float s = 0.f;
        for (int k = 0; k < H; ++k) s += ar[k] * Wn[(size_t)k * H + t] + cr[k] * W2[(size_t)k * H + t];
        outp[(size_t)r * H + t] = (s >= 0.f) ? s : s * SLOPE;
    }
}

// ---------------- CSR scan (single block) ----------------
__global__ __launch_bounds__(1024) void scan_k(const int* __restrict__ cnt, int* __restrict__ off,
                                               int* __restrict__ cur, int n) {
    __shared__ int part[1024];
    int tid = threadIdx.x;
    int per = (n + 1023) / 1024;
    int s0 = tid * per;
    int e0 = s0 + per; if (e0 > n) e0 = n;
    int sum = 0;
    for (int i = s0; i < e0; ++i) sum += cnt[i];
    part[tid] = sum;
    __syncthreads();
    for (int d = 1; d < 1024; d <<= 1) {
        int v = (tid >= d) ? part[tid - d] : 0;
        __syncthreads();
        part[tid] += v;
        __syncthreads();
    }
    int excl = (tid == 0) ? 0 : part[tid - 1];
    for (int i = s0; i < e0; ++i) { off[i] = excl; cur[i] = excl; excl += cnt[i]; }
    if (tid == 1023) off[n] = excl;
}

__global__ void scatter_k(const int* __restrict__ dst, const int* __restrict__ src,
                          const int* __restrict__ et, int* __restrict__ cur,
                          int* __restrict__ psrc, int* __restrict__ pet, int nE) {
    int e = blockIdx.x * blockDim.x + threadIdx.x;
    if (e < nE) {
        int p = atomicAdd(&cur[dst[e]], 1);
        psrc[p] = src[e];
        pet[p] = et[e];
    }
}

__global__ void zlist_k(const int* __restrict__ cnt, int* __restrict__ zl, int* __restrict__ nz, int n) {
    int v = blockIdx.x * blockDim.x + threadIdx.x;
    if (v < n && cnt[v] == 0) {
        int p = atomicAdd(nz, 1);
        zl[p] = v;
    }
}

// ---------------- entity raw message aggregation via CSR (wave per dst) ----------------
__global__ __launch_bounds__(256) void ent_agg_k(const float* __restrict__ cur, const float* __restrict__ rel,
                                                 const int* __restrict__ eoff, const int* __restrict__ esrc,
                                                 const int* __restrict__ eet, float* __restrict__ agg, int n) {
    int wave = threadIdx.x >> 6, lane = threadIdx.x & 63;
    int v = blockIdx.x * 4 + wave;
    if (v >= n) return;
    float a0 = 0.f, a1 = 0.f, a2 = 0.f, a3 = 0.f;
    int c3 = lane + 192;
    int beg = eoff[v], end = eoff[v + 1];
    for (int i = beg; i < end; ++i) {
        const float* hr = cur + (size_t)esrc[i] * H;
        const float* rr = rel + (size_t)eet[i] * H;
        a0 += hr[lane] + rr[lane];
        a1 += hr[lane + 64] + rr[lane + 64];
        a2 += hr[lane + 128] + rr[lane + 128];
        if (c3 < H) a3 += hr[c3] + rr[c3];
    }
    float* o = agg + (size_t)v * H;
    o[lane] = a0; o[lane + 64] = a1; o[lane + 128] = a2;
    if (c3 < H) o[c3] = a3;
}

// ---------------- generic tiled SGEMM ----------------
// BT=0: C[m][n] = sum_k A[m][k]*B[k][n]  (B K-major, ldb = Nc)
// BT=1: C[m][n] = sum_k A[m][k]*B[n][k]  (B row-major out x in, ldb = 200)
// DUAL: K=400 split at 200 between (A1,B1) and (A2,B2); else K=200.
template <int BT, int DUAL, int RELU>
__global__ __launch_bounds__(256) void gemm_k(const float* __restrict__ A1, const float* __restrict__ A2,
                                              const float* __restrict__ B1, const float* __restrict__ B2,
                                              float* __restrict__ C, int M, int Nc) {
    __shared__ float As[8][68];
    __shared__ float Bs[8][68];
    const int tid = threadIdx.x;
    const int m0 = blockIdx.x * 64;
    const int n0 = blockIdx.y * 64;
    const int tx = tid & 15, ty = tid >> 4;
    float acc[4][4] = {{0.f, 0.f, 0.f, 0.f}, {0.f, 0.f, 0.f, 0.f}, {0.f, 0.f, 0.f, 0.f}, {0.f, 0.f, 0.f, 0.f}};
    const int KTOT = DUAL ? 400 : 200;
    for (int k0 = 0; k0 < KTOT; k0 += 8) {
        const float* Ap; const float* Bp; int kk;
        if (DUAL && k0 >= 200) { Ap = A2; Bp = B2; kk = k0 - 200; }
        else { Ap = A1; Bp = B1; kk = k0; }
#pragma unroll
        for (int i = 0; i < 2; ++i) {
            int lin = tid + i * 256;
            int ml = lin >> 3, kl = lin & 7;
            int m = m0 + ml;
            As[kl][ml] = (m < M) ? Ap[(size_t)m * 200 + kk + kl] : 0.f;
        }
#pragma unroll
        for (int i = 0; i < 2; ++i) {
            int lin = tid + i * 256;
            if (BT) {
                int nl = lin >> 3, kl = lin & 7;
                int n = n0 + nl;
                Bs[kl][nl] = (n < Nc) ? Bp[(size_t)n * 200 + kk + kl] : 0.f;
            } else {
                int kl = lin >> 6, nl = lin & 63;
                int n = n0 + nl;
                Bs[kl][nl] = (n < Nc) ? Bp[(size_t)(kk + kl) * Nc + n] : 0.f;
            }
        }
        __syncthreads();
#pragma unroll
        for (int k = 0; k < 8; ++k) {
            float4 av = *(const float4*)(&As[k][ty * 4]);
            float4 bv = *(const float4*)(&Bs[k][tx * 4]);
            acc[0][0] += av.x * bv.x; acc[0][1] += av.x * bv.y; acc[0][2] += av.x * bv.z; acc[0][3] += av.x * bv.w;
            acc[1][0] += av.y * bv.x; acc[1][1] += av.y * bv.y; acc[1][2] += av.y * bv.z; acc[1][3] += av.y * bv.w;
            acc[2][0] += av.z * bv.x; acc[2][1] += av.z * bv.y; acc[2][2] += av.z * bv.z; acc[2][3] += av.z * bv.w;
            acc[3][0] += av.w * bv.x; acc[3][1] += av.w * bv.y; acc[3][2] += av.w * bv.z; acc[3][3] += av.w * bv.w;
        }
        __syncthreads();
    }
#pragma unroll
    for (int i = 0; i < 4; ++i) {
        int m = m0 + ty * 4 + i;
        if (m >= M) continue;
#pragma unroll
        for (int j = 0; j < 4; ++j) {
            int n = n0 + tx * 4 + j;
            if (n >= Nc) continue;
            float v = acc[i][j];
            if (RELU) v = (v >= 0.f) ? v : v * SLOPE;
            C[(size_t)m * Nc + n] = v;
        }
    }
}

// ---------------- fixup for zero-indeg rows: out[row] = rrelu(h[row] @ Wl) ----------------
__global__ __launch_bounds__(256) void fixup_k(const float* __restrict__ h, const float* __restrict__ Wl,
                                               const int* __restrict__ zl, const int* __restrict__ nz,
                                               float* __restrict__ outp) {
    __shared__ float xr[H];
    int nzv = *nz;
    for (int z = blockIdx.x; z < nzv; z += gridDim.x) {
        int row = zl[z];
        if (threadIdx.x < H) xr[threadIdx.x] = h[(size_t)row * H + threadIdx.x];
        __syncthreads();
        if (threadIdx.x < H) {
            float s = 0.f;
            for (int k = 0; k < H; ++k) s += xr[k] * Wl[(size_t)k * H + threadIdx.x];
            outp[(size_t)row * H + threadIdx.x] = (s >= 0.f) ? s : s * SLOPE;
        }
        __syncthreads();
    }
}

// ---------------- entity GRU combine (elementwise over chunk) ----------------
__global__ __launch_bounds__(256) void gru_comb_k(const float* __restrict__ gi, const float* __restrict__ gh,
                                                  const float* __restrict__ bih, const float* __restrict__ bhh,
                                                  const float* __restrict__ h, float* __restrict__ outp,
                                                  int rows, int row0) {
    int idx = blockIdx.x * 256 + threadIdx.x;
    if (idx >= rows * H) return;
    int rl = idx / H;
    int c = idx - rl * H;
    int gr = row0 + rl;
    float ir = gi[(size_t)rl * 600 + c] + bih[c];
    float iz = gi[(size_t)rl * 600 + 200 + c] + bih[200 + c];
    float in_ = gi[(size_t)rl * 600 + 400 + c] + bih[400 + c];
    float hr = gh[(size_t)rl * 600 + c] + bhh[c];
    float hz = gh[(size_t)rl * 600 + 200 + c] + bhh[200 + c];
    float hn = gh[(size_t)rl * 600 + 400 + c] + bhh[400 + c];
    float rr = sigf(ir + hr);
    float zz = sigf(iz + hz);
    float nn = tanhf(in_ + rr * hn);
    outp[(size_t)gr * H + c] = (1.f - zz) * nn + zz * h[(size_t)gr * H + c];
}

// =========================== host orchestration ===========================
extern "C" void kernel_launch(void* const* d_in, const int* in_sizes, int n_in,
                              void* d_out, int out_size, void* d_ws, size_t ws_size,
                              hipStream_t stream) {
    (void)in_sizes; (void)n_in; (void)out_size; (void)ws_size;
    const int* src  = (const int*)d_in[0];
    const int* dst  = (const int*)d_in[1];
    const int* etyp = (const int*)d_in[2];
    const int* rte  = (const int*)d_in[3];
    const int* rseg = (const int*)d_in[4];
    const int* ssrc = (const int*)d_in[5];
    const int* sdst = (const int*)d_in[6];
    const int* setp = (const int*)d_in[7];
    const int* srte = (const int*)d_in[8];
    const int* srseg= (const int*)d_in[9];
    const float* dyn     = (const float*)d_in[10];
    const float* emb_rel = (const float*)d_in[11];
    const float* p_rel   = (const float*)d_in[12];
    const float* Wih1 = (const float*)d_in[13]; const float* Whh1 = (const float*)d_in[14];
    const float* bih1 = (const float*)d_in[15]; const float* bhh1 = (const float*)d_in[16];
    const float* Wih2 = (const float*)d_in[17]; const float* Whh2 = (const float*)d_in[18];
    const float* bih2 = (const float*)d_in[19]; const float* bhh2 = (const float*)d_in[20];
    const float* Wih3 = (const float*)d_in[21]; const float* Whh3 = (const float*)d_in[22];
    const float* bih3 = (const float*)d_in[23]; const float* bhh3 = (const float*)d_in[24];
    const float* Wihe = (const float*)d_in[25]; const float* Whhe = (const float*)d_in[26];
    const float* bihe = (const float*)d_in[27]; const float* bhhe = (const float*)d_in[28];
    const float* Wn  = (const float*)d_in[29];
    const float* Wl  = (const float*)d_in[30];
    const float* We  = (const float*)d_in[31];
    const float* sWn = (const float*)d_in[32];
    const float* sWl = (const float*)d_in[33];
    const float* sWe = (const float*)d_in[34];

    float* out = (float*)d_out;
    const size_t NH = (size_t)N_NODES * H;
    float* relout = out + 3 * NH;

    char* wp = (char*)d_ws;
    auto carve = [&](size_t bytes) -> void* {
        void* p = (void*)wp;
        wp += (bytes + 255) & ~(size_t)255;
        return p;
    };
    float* wsH  = (float*)carve(NH * 4);
    float* wsX  = (float*)carve(NH * 4);  // agg0 during layers, GI/GH during GRU
    float* h0a  = (float*)carve((size_t)R2 * H * 4);
    float* c0b  = (float*)carve((size_t)R2 * H * 4);
    float* xin  = (float*)carve((size_t)R2 * H * 4);
    float* srelA= (float*)carve((size_t)R2 * H * 4);
    float* srelB= (float*)carve((size_t)R2 * H * 4);
    float* sagg = (float*)carve((size_t)R2 * H * 4);
    float* sxin = (float*)carve((size_t)SR * H * 4);
    float* p_h  = (float*)carve((size_t)SR * H * 4);
    float* p_c  = (float*)carve((size_t)SR * H * 4);
    int* ecnt  = (int*)carve((size_t)N_NODES * 4);
    int* eoff  = (int*)carve((size_t)(N_NODES + 1) * 4);
    int* ecur  = (int*)carve((size_t)N_NODES * 4);
    int* esrcp = (int*)carve((size_t)E_EDGES * 4);
    int* eetp  = (int*)carve((size_t)E_EDGES * 4);
    int* zl    = (int*)carve((size_t)N_NODES * 4);
    int* nz    = (int*)carve(4);
    int* rcnt  = (int*)carve((size_t)R2 * 4);
    int* scnt  = (int*)carve((size_t)SR * 4);
    int* sindeg= (int*)carve((size_t)R2 * 4);

    // h = l2norm(dynamic_emb)
    l2norm_k<<<N_NODES, 256, 0, stream>>>(dyn, wsH, N_NODES);

    for (int t = 0; t < T_STEPS; ++t) {
        const int* src_t  = src + (size_t)t * E_EDGES;
        const int* dst_t  = dst + (size_t)t * E_EDGES;
        const int* et_t   = etyp + (size_t)t * E_EDGES;
        const int* rte_t  = rte + (size_t)t * R2E;
        const int* rseg_t = rseg + (size_t)t * R2E;
        const int* ssrc_t = ssrc + (size_t)t * SE_EDGES;
        const int* sdst_t = sdst + (size_t)t * SE_EDGES;
        const int* set_t  = setp + (size_t)t * SE_EDGES;
        const int* srte_t = srte + (size_t)t * S2E;
        const int* srseg_t= srseg + (size_t)t * S2E;

        // buffer plan (uses future output slots as scratch; all re-written later)
        float* hin  = (t == 0) ? wsH : out + (size_t)(t - 1) * NH;
        float* Abuf = (t == 0) ? out + NH : wsH;
        float* Bbuf = out + 2 * NH;
        float* hist = out + (size_t)t * NH;
        float* rel_t = relout + (size_t)t * R2 * H;
        const float* hprev = (t == 0) ? emb_rel : relout + (size_t)(t - 1) * R2 * H;
        const float* cprev = (t == 0) ? xin : c0b;
        const float* php   = (t == 0) ? p_rel : p_h;
        const float* pcp   = (t == 0) ? sxin : p_c;

        // ---- x_input = seg_mean(h[r_to_e], r_seg, R2) ----
        hipMemsetAsync(xin, 0, (size_t)R2 * H * 4, stream);
        hipMemsetAsync(rcnt, 0, (size_t)R2 * 4, stream);
        seg_cnt_k<<<64, 256, 0, stream>>>(rseg_t, R2E, rcnt, R2);
        seg_acc_k<<<64 * 8, 256, 0, stream>>>(hin, rte_t, rseg_t, R2E, xin, R2);
        seg_div_k<<<(R2 * H + 255) / 256, 256, 0, stream>>>(xin, rcnt, R2);
        // ---- LSTM1 ----
        lstm_k<<<R2, 256, 0, stream>>>(emb_rel, xin, hprev, cprev, Wih1, Whh1, bih1, bhh1, h0a, c0b, R2);
        // ---- sx = seg_mean(h_0[s_r_to_e], s_r_seg, SR) ----
        hipMemsetAsync(sxin, 0, (size_t)SR * H * 4, stream);
        hipMemsetAsync(scnt, 0, (size_t)SR * 4, stream);
        seg_cnt_k<<<8, 256, 0, stream>>>(srseg_t, S2E, scnt, SR);
        seg_acc_k<<<16 * 8, 256, 0, stream>>>(h0a, srte_t, srseg_t, S2E, sxin, SR);
        seg_div_k<<<(SR * H + 255) / 256, 256, 0, stream>>>(sxin, scnt, SR);
        // ---- LSTM2 ----
        lstm_k<<<SR, 256, 0, stream>>>(p_rel, sxin, php, pcp, Wih2, Whh2, bih2, bhh2, p_h, p_c, SR);
        // ---- super RGCN (2 layers) ----
        hipMemsetAsync(sindeg, 0, (size_t)R2 * 4, stream);
        cnt_k<<<(SE_EDGES + 255) / 256, 256, 0, stream>>>(sdst_t, SE_EDGES, sindeg);
        hipMemsetAsync(sagg, 0, (size_t)R2 * H * 4, stream);
        sup_agg_k<<<SE_EDGES, 256, 0, stream>>>(h0a, p_h, ssrc_t, sdst_t, set_t, sagg, SE_EDGES);
        sup_comb_k<<<R2, 256, 0, stream>>>(sagg, h0a, sWn, sWe, sWl, sindeg, srelA);
        hipMemsetAsync(sagg, 0, (size_t)R2 * H * 4, stream);
        sup_agg_k<<<SE_EDGES, 256, 0, stream>>>(srelA, p_h, ssrc_t, sdst_t, set_t, sagg, SE_EDGES);
        sup_comb_k<<<R2, 256, 0, stream>>>(sagg, srelA, sWn + H * H, sWe + H * H, sWl + H * H, sindeg, srelB);
        l2norm_k<<<R2, 256, 0, stream>>>(srelB, srelB, R2);
        // ---- rel GRU -> rel_embs[t] ----
        gru_small_k<<<R2, 256, 0, stream>>>(srelB, h0a, Wih3, Whh3, bih3, bhh3, rel_t, R2);

        // ---- entity CSR build (shared by both layers) ----
        hipMemsetAsync(ecnt, 0, (size_t)N_NODES * 4, stream);
        hipMemsetAsync(nz, 0, 4, stream);
        cnt_k<<<(E_EDGES + 255) / 256, 256, 0, stream>>>(dst_t, E_EDGES, ecnt);
        scan_k<<<1, 1024, 0, stream>>>(ecnt, eoff, ecur, N_NODES);
        scatter_k<<<(E_EDGES + 255) / 256, 256, 0, stream>>>(dst_t, src_t, et_t, ecur, esrcp, eetp, E_EDGES);
        zlist_k<<<(N_NODES + 255) / 256, 256, 0, stream>>>(ecnt, zl, nz, N_NODES);

        dim3 gl((N_NODES + 63) / 64, (H + 63) / 64);
        // ---- entity layer 0 ----
        ent_agg_k<<<(N_NODES + 3) / 4, 256, 0, stream>>>(hin, rel_t, eoff, esrcp, eetp, wsX, N_NODES);
        gemm_k<0, 1, 1><<<gl, 256, 0, stream>>>(wsX, hin, Wn, We, Abuf, N_NODES, H);
        fixup_k<<<2048, 256, 0, stream>>>(hin, Wl, zl, nz, Abuf);
        // ---- entity layer 1 ----
        ent_agg_k<<<(N_NODES + 3) / 4, 256, 0, stream>>>(Abuf, rel_t, eoff, esrcp, eetp, wsX, N_NODES);
        gemm_k<0, 1, 1><<<gl, 256, 0, stream>>>(wsX, Abuf, Wn + H * H, We + H * H, Bbuf, N_NODES, H);
        fixup_k<<<2048, 256, 0, stream>>>(Abuf, Wl + H * H, zl, nz, Bbuf);
        l2norm_k<<<N_NODES, 256, 0, stream>>>(Bbuf, Bbuf, N_NODES);

        // ---- entity GRU (chunked GI/GH GEMMs + combine) ----
        const int CHUNK = 16000;  // CHUNK*1200 floats fits in wsX (N*H = 20e6)
        for (int r0 = 0; r0 < N_NODES; r0 += CHUNK) {
            int rows = (N_NODES - r0 < CHUNK) ? (N_NODES - r0) : CHUNK;
            float* GI = wsX;
            float* GH = wsX + (size_t)CHUNK * 600;
            dim3 gg((rows + 63) / 64, (600 + 63) / 64);
            gemm_k<1, 0, 0><<<gg, 256, 0, stream>>>(Bbuf + (size_t)r0 * H, nullptr, Wihe, nullptr, GI, rows, 600);
            gemm_k<1, 0, 0><<<gg, 256, 0, stream>>>(hin + (size_t)r0 * H, nullptr, Whhe, nullptr, GH, rows, 600);
            gru_comb_k<<<(rows * H + 255) / 256, 256, 0, stream>>>(GI, GH, bihe, bhhe, hin, hist, rows, r0);
        }
        l2norm_k<<<N_NODES, 256, 0, stream>>>(hist, hist, N_NODES);
    }
}

// Round 2
// 6813.327 us; speedup vs baseline: 1.5238x; 1.5238x over previous
//
#include <hip/hip_runtime.h>
#include <math.h>

#define N_NODES 100000
#define H 200
#define R2 500
#define T_STEPS 3
#define E_EDGES 300000
#define R2E 400000
#define SE_EDGES 4000
#define SR 8
#define S2E 8000
#define SLOPE 0.22916666666666666f

static __device__ __forceinline__ float sigf(float x) { return 1.f / (1.f + expf(-x)); }

// ---------------- l2 normalize rows (src may alias dst) ----------------
__global__ __launch_bounds__(256) void l2norm_k(const float* __restrict__ src,
                                                float* __restrict__ dst, int rows) {
    int r = blockIdx.x;
    if (r >= rows) return;
    int t = threadIdx.x;
    float v = (t < H) ? src[(size_t)r * H + t] : 0.f;
    float s = v * v;
    for (int o = 32; o > 0; o >>= 1) s += __shfl_down(s, o);
    __shared__ float red[4];
    if ((t & 63) == 0) red[t >> 6] = s;
    __syncthreads();
    if (t == 0) red[0] = 1.f / fmaxf(sqrtf(red[0] + red[1] + red[2] + red[3]), 1e-12f);
    __syncthreads();
    if (t < H) dst[(size_t)r * H + t] = v * red[0];
}

// ---------------- generic counting ----------------
__global__ void cnt_k(const int* __restrict__ d, int n, int* __restrict__ cnt) {
    int i = blockIdx.x * blockDim.x + threadIdx.x;
    if (i < n) atomicAdd(&cnt[d[i]], 1);
}

// ---------------- segment counts with LDS hierarchy ----------------
__global__ __launch_bounds__(256) void seg_cnt_k(const int* __restrict__ seg, int n,
                                                 int* __restrict__ cnt, int nseg) {
    __shared__ int lc[500];
    for (int i = threadIdx.x; i < nseg; i += 256) lc[i] = 0;
    __syncthreads();
    int chunk = (n + gridDim.x - 1) / gridDim.x;
    int beg = blockIdx.x * chunk;
    int end = beg + chunk; if (end > n) end = n;
    for (int i = beg + threadIdx.x; i < end; i += 256) atomicAdd(&lc[seg[i]], 1);
    __syncthreads();
    for (int i = threadIdx.x; i < nseg; i += 256) if (lc[i]) atomicAdd(&cnt[i], lc[i]);
}

// ---------------- small segment sum (SR path), LDS col-chunked ----------------
#define SEG_CW 25
__global__ __launch_bounds__(256) void seg_acc_k(const float* __restrict__ hsrc,
                                                 const int* __restrict__ idx,
                                                 const int* __restrict__ seg, int n,
                                                 float* __restrict__ acc, int nseg) {
    __shared__ float lacc[500 * SEG_CW];
    int cg = blockIdx.x & 7;
    int pb = blockIdx.x >> 3;
    int NPB = gridDim.x >> 3;
    int t = threadIdx.x;
    for (int i = t; i < nseg * SEG_CW; i += 256) lacc[i] = 0.f;
    __syncthreads();
    int chunk = (n + NPB - 1) / NPB;
    int beg = pb * chunk;
    int end = beg + chunk; if (end > n) end = n;
    if (t < 250) {
        int il = t / SEG_CW;
        int c = t - il * SEG_CW;
        int col = cg * SEG_CW + c;
        for (int i = beg + il; i < end; i += 10) {
            int r = seg[i];
            int e = idx[i];
            atomicAdd(&lacc[r * SEG_CW + c], hsrc[(size_t)e * H + col]);
        }
    }
    __syncthreads();
    for (int i = t; i < nseg * SEG_CW; i += 256) {
        int r = i / SEG_CW, c = i - (i / SEG_CW) * SEG_CW;
        atomicAdd(&acc[(size_t)r * H + cg * SEG_CW + c], lacc[i]);
    }
}

__global__ void seg_div_k(float* __restrict__ acc, const int* __restrict__ cnt, int rows) {
    int i = blockIdx.x * blockDim.x + threadIdx.x;
    if (i < rows * H) {
        int c = cnt[i / H];
        acc[i] /= (float)(c > 0 ? c : 1);
    }
}

// ---------------- segment permutation scatter ----------------
__global__ void seg_scatter_k(const int* __restrict__ seg, const int* __restrict__ val,
                              int* __restrict__ cur, int* __restrict__ outp, int n) {
    int i = blockIdx.x * blockDim.x + threadIdx.x;
    if (i < n) {
        int p = atomicAdd(&cur[seg[i]], 1);
        outp[p] = val[i];
    }
}

// ---------------- CSR segment mean: one block per segment, coalesced rows ----------------
__global__ __launch_bounds__(256) void seg_mean_csr_k(const float* __restrict__ h,
                                                      const int* __restrict__ per,
                                                      const int* __restrict__ off,
                                                      float* __restrict__ xout, int nseg) {
    int r = blockIdx.x;
    if (r >= nseg) return;
    int t = threadIdx.x;
    int beg = off[r], end = off[r + 1];
    if (t >= H) return;
    float acc = 0.f;
    int i = beg;
    for (; i + 4 <= end; i += 4) {
        int e0 = per[i], e1 = per[i + 1], e2 = per[i + 2], e3 = per[i + 3];
        float v0 = h[(size_t)e0 * H + t];
        float v1 = h[(size_t)e1 * H + t];
        float v2 = h[(size_t)e2 * H + t];
        float v3 = h[(size_t)e3 * H + t];
        acc += v0 + v1 + v2 + v3;
    }
    for (; i < end; ++i) acc += h[(size_t)per[i] * H + t];
    float c = (float)(end - beg);
    xout[(size_t)r * H + t] = acc / fmaxf(c, 1.f);
}

// ---------------- fused LSTM cell + l2norm of h and c ----------------
__global__ __launch_bounds__(256) void lstm_k(const float* __restrict__ x1, const float* __restrict__ x2,
                                              const float* __restrict__ hprev, const float* __restrict__ cprev,
                                              const float* __restrict__ Wih, const float* __restrict__ Whh,
                                              const float* __restrict__ bih, const float* __restrict__ bhh,
                                              float* __restrict__ hout, float* __restrict__ cout, int rows) {
    int r = blockIdx.x;
    if (r >= rows) return;
    __shared__ float xb[2 * H], hb[H], gb[4 * H], hv[H], cv[H];
    __shared__ float red[8];
    int t = threadIdx.x;
    for (int i = t; i < 2 * H; i += 256)
        xb[i] = (i < H) ? x1[(size_t)r * H + i] : x2[(size_t)r * H + i - H];
    if (t < H) hb[t] = hprev[(size_t)r * H + t];
    __syncthreads();
    for (int j = t; j < 4 * H; j += 256) {
        float s = bih[j] + bhh[j];
        const float* wi = Wih + (size_t)j * 2 * H;
        for (int k = 0; k < 2 * H; ++k) s += xb[k] * wi[k];
        const float* wh = Whh + (size_t)j * H;
        for (int k = 0; k < H; ++k) s += hb[k] * wh[k];
        gb[j] = s;
    }
    __syncthreads();
    if (t < H) {
        float ig = sigf(gb[t]);
        float fg = sigf(gb[H + t]);
        float gg = tanhf(gb[2 * H + t]);
        float og = sigf(gb[3 * H + t]);
        float c2 = fg * cprev[(size_t)r * H + t] + ig * gg;
        cv[t] = c2;
        hv[t] = og * tanhf(c2);
    }
    __syncthreads();
    float sh = 0.f, sc = 0.f;
    if (t < H) { sh = hv[t] * hv[t]; sc = cv[t] * cv[t]; }
    for (int o = 32; o > 0; o >>= 1) { sh += __shfl_down(sh, o); sc += __shfl_down(sc, o); }
    if ((t & 63) == 0) { red[t >> 6] = sh; red[4 + (t >> 6)] = sc; }
    __syncthreads();
    if (t == 0) {
        red[0] = 1.f / fmaxf(sqrtf(red[0] + red[1] + red[2] + red[3]), 1e-12f);
        red[4] = 1.f / fmaxf(sqrtf(red[4] + red[5] + red[6] + red[7]), 1e-12f);
    }
    __syncthreads();
    if (t < H) {
        hout[(size_t)r * H + t] = hv[t] * red[0];
        cout[(size_t)r * H + t] = cv[t] * red[4];
    }
}

// ---------------- fused small GRU + l2norm ----------------
__global__ __launch_bounds__(256) void gru_small_k(const float* __restrict__ x, const float* __restrict__ h,
                                                   const float* __restrict__ Wih, const float* __restrict__ Whh,
                                                   const float* __restrict__ bih, const float* __restrict__ bhh,
                                                   float* __restrict__ outp, int rows) {
    int r = blockIdx.x;
    if (r >= rows) return;
    __shared__ float xb[H], hb[H], gi[3 * H], gh[3 * H], ov[H];
    __shared__ float red[4];
    int t = threadIdx.x;
    if (t < H) { xb[t] = x[(size_t)r * H + t]; hb[t] = h[(size_t)r * H + t]; }
    __syncthreads();
    for (int j = t; j < 3 * H; j += 256) {
        float si = bih[j], sh2 = bhh[j];
        const float* wi = Wih + (size_t)j * H;
        const float* wh = Whh + (size_t)j * H;
        for (int k = 0; k < H; ++k) { si += xb[k] * wi[k]; sh2 += hb[k] * wh[k]; }
        gi[j] = si; gh[j] = sh2;
    }
    __syncthreads();
    if (t < H) {
        float rr = sigf(gi[t] + gh[t]);
        float zz = sigf(gi[H + t] + gh[H + t]);
        float nn = tanhf(gi[2 * H + t] + rr * gh[2 * H + t]);
        ov[t] = (1.f - zz) * nn + zz * hb[t];
    }
    __syncthreads();
    float s = (t < H) ? ov[t] * ov[t] : 0.f;
    for (int o = 32; o > 0; o >>= 1) s += __shfl_down(s, o);
    if ((t & 63) == 0) red[t >> 6] = s;
    __syncthreads();
    if (t == 0) red[0] = 1.f / fmaxf(sqrtf(red[0] + red[1] + red[2] + red[3]), 1e-12f);
    __syncthreads();
    if (t < H) outp[(size_t)r * H + t] = ov[t] * red[0];
}

// ---------------- super-graph raw message aggregation ----------------
__global__ __launch_bounds__(256) void sup_agg_k(const float* __restrict__ cur, const float* __restrict__ prel,
                                                 const int* __restrict__ ss, const int* __restrict__ sd,
                                                 const int* __restrict__ se, float* __restrict__ sagg, int nE) {
    int e = blockIdx.x;
    if (e >= nE) return;
    int t = threadIdx.x;
    if (t < H) {
        int s = ss[e], d = sd[e], et = se[e];
        float v = cur[(size_t)s * H + t] + prel[(size_t)et * H + t];
        atomicAdd(&sagg[(size_t)d * H + t], v);
    }
}

// ---------------- super-graph combine: rrelu(agg@Wn + cur@Wsel) ----------------
__global__ __launch_bounds__(256) void sup_comb_k(const float* __restrict__ agg, const float* __restrict__ cur,
                                                  const float* __restrict__ Wn, const float* __restrict__ We,
                                                  const float* __restrict__ Wl, const int* __restrict__ indeg,
                                                  float* __restrict__ outp) {
    int r = blockIdx.x;
    __shared__ float ar[H], cr[H];
    int t = threadIdx.x;
    if (t < H) { ar[t] = agg[(size_t)r * H + t]; cr[t] = cur[(size_t)r * H + t]; }
    __syncthreads();
    const float* W2 = (indeg[r] > 0) ? We : Wl;
    if (t < H) {
        float s = 0.f;
        for (int k = 0; k < H; ++k) s += ar[k] * Wn[(size_t)k * H + t] + cr[k] * W2[(size_t)k * H + t];
        outp[(size_t)r * H + t] = (s >= 0.f) ? s : s * SLOPE;
    }
}

// ---------------- CSR scan (single block) ----------------
__global__ __launch_bounds__(1024) void scan_k(const int* __restrict__ cnt, int* __restrict__ off,
                                               int* __restrict__ cur, int n) {
    __shared__ int part[1024];
    int tid = threadIdx.x;
    int per = (n + 1023) / 1024;
    int s0 = tid * per;
    int e0 = s0 + per; if (e0 > n) e0 = n;
    int sum = 0;
    for (int i = s0; i < e0; ++i) sum += cnt[i];
    part[tid] = sum;
    __syncthreads();
    for (int d = 1; d < 1024; d <<= 1) {
        int v = (tid >= d) ? part[tid - d] : 0;
        __syncthreads();
        part[tid] += v;
        __syncthreads();
    }
    int excl = (tid == 0) ? 0 : part[tid - 1];
    for (int i = s0; i < e0; ++i) { off[i] = excl; cur[i] = excl; excl += cnt[i]; }
    if (tid == 1023) off[n] = excl;
}

__global__ void scatter_k(const int* __restrict__ dst, const int* __restrict__ src,
                          const int* __restrict__ et, int* __restrict__ cur,
                          int* __restrict__ psrc, int* __restrict__ pet, int nE) {
    int e = blockIdx.x * blockDim.x + threadIdx.x;
    if (e < nE) {
        int p = atomicAdd(&cur[dst[e]], 1);
        psrc[p] = src[e];
        pet[p] = et[e];
    }
}

__global__ void zlist_k(const int* __restrict__ cnt, int* __restrict__ zl, int* __restrict__ nz, int n) {
    int v = blockIdx.x * blockDim.x + threadIdx.x;
    if (v < n && cnt[v] == 0) {
        int p = atomicAdd(nz, 1);
        zl[p] = v;
    }
}

// ---------------- entity raw message aggregation via CSR (wave per dst) ----------------
__global__ __launch_bounds__(256) void ent_agg_k(const float* __restrict__ cur, const float* __restrict__ rel,
                                                 const int* __restrict__ eoff, const int* __restrict__ esrc,
                                                 const int* __restrict__ eet, float* __restrict__ agg, int n) {
    int wave = threadIdx.x >> 6, lane = threadIdx.x & 63;
    int v = blockIdx.x * 4 + wave;
    if (v >= n) return;
    float a0 = 0.f, a1 = 0.f, a2 = 0.f, a3 = 0.f;
    int c3 = lane + 192;
    int beg = eoff[v], end = eoff[v + 1];
    for (int i = beg; i < end; ++i) {
        const float* hr = cur + (size_t)esrc[i] * H;
        const float* rr = rel + (size_t)eet[i] * H;
        a0 += hr[lane] + rr[lane];
        a1 += hr[lane + 64] + rr[lane + 64];
        a2 += hr[lane + 128] + rr[lane + 128];
        if (c3 < H) a3 += hr[c3] + rr[c3];
    }
    float* o = agg + (size_t)v * H;
    o[lane] = a0; o[lane + 64] = a1; o[lane + 128] = a2;
    if (c3 < H) o[c3] = a3;
}

// ---------------- bf16 MFMA GEMM ----------------
// C[M][Nc] (fp32) = A @ B, A fp32 row-major lda=200 (per source), K=200 per source.
// BT=1: B fp32 row-major [Nc][200] (out x in, i.e. C = A @ B^T)
// BT=0: B fp32 K-major [200][Nc]
// DUAL=1: C = A1@B1 + A2@B2 (two K=200 sources)
// RELU=1: rrelu epilogue
#define GBM 128
#define GBN 64
#define LDT 40  // LDS row stride in bf16 elems (80B: 2-way bank aliasing only)

template <int BT, int DUAL, int RELU>
__global__ __launch_bounds__(256, 2) void gemm_bf16_k(const float* __restrict__ A1, const float* __restrict__ A2,
                                                      const float* __restrict__ B1, const float* __restrict__ B2,
                                                      float* __restrict__ C, int M, int Nc) {
    typedef __bf16 bf8 __attribute__((ext_vector_type(8)));
    typedef __bf16 bf4 __attribute__((ext_vector_type(4)));
    typedef float f32x4 __attribute__((ext_vector_type(4)));
    __shared__ __bf16 Asm[GBM * LDT];
    __shared__ __bf16 Bsm[GBN * LDT];
    const int tid = threadIdx.x;
    const int m0 = blockIdx.x * GBM;
    const int n0 = blockIdx.y * GBN;
    const int w = tid >> 6, lane = tid & 63;
    const int wr = w >> 1, wc = w & 1;
    const int lr = lane & 15, lo = lane >> 4;
    f32x4 acc[4][2];
#pragma unroll
    for (int i = 0; i < 4; ++i)
#pragma unroll
        for (int j = 0; j < 2; ++j)
#pragma unroll
            for (int e = 0; e < 4; ++e) acc[i][j][e] = 0.f;

    const int NT = DUAL ? 14 : 7;
    for (int kt = 0; kt < NT; ++kt) {
        const float* Ap = (DUAL && kt >= 7) ? A2 : A1;
        const float* Bp = (DUAL && kt >= 7) ? B2 : B1;
        const int k0 = (DUAL && kt >= 7) ? (kt - 7) * 32 : kt * 32;
        if (kt) __syncthreads();
        // ---- stage A tile: [128 rows][32 k] fp32 -> bf16 ----
        {
            int row = tid >> 1, half = tid & 1;
            int m = m0 + row;
#pragma unroll
            for (int j = 0; j < 4; ++j) {
                int k = k0 + half * 16 + j * 4;
                float4 v = make_float4(0.f, 0.f, 0.f, 0.f);
                if (m < M && k < 200) v = *(const float4*)(Ap + (size_t)m * 200 + k);
                bf4 b;
                b[0] = (__bf16)v.x; b[1] = (__bf16)v.y; b[2] = (__bf16)v.z; b[3] = (__bf16)v.w;
                *(bf4*)(&Asm[row * LDT + half * 16 + j * 4]) = b;
            }
        }
        // ---- stage B tile: Bsm[n][k] ----
        if (BT) {
            int row = tid >> 2, q = tid & 3;
            int n = n0 + row;
#pragma unroll
            for (int j = 0; j < 2; ++j) {
                int k = k0 + q * 8 + j * 4;
                float4 v = make_float4(0.f, 0.f, 0.f, 0.f);
                if (n < Nc && k < 200) v = *(const float4*)(Bp + (size_t)n * 200 + k);
                bf4 b;
                b[0] = (__bf16)v.x; b[1] = (__bf16)v.y; b[2] = (__bf16)v.z; b[3] = (__bf16)v.w;
                *(bf4*)(&Bsm[row * LDT + q * 8 + j * 4]) = b;
            }
        } else {
            int kl = tid >> 3, nb = (tid & 7) * 8;
#pragma unroll
            for (int j = 0; j < 8; ++j) {
                int nl = nb + j;
                int n = n0 + nl, k = k0 + kl;
                float v = (n < Nc && k < 200) ? Bp[(size_t)k * Nc + n] : 0.f;
                Bsm[nl * LDT + kl] = (__bf16)v;
            }
        }
        __syncthreads();
        // ---- fragments + MFMA ----
        bf8 af[4], bfr[2];
#pragma unroll
        for (int mf = 0; mf < 4; ++mf)
            af[mf] = *(const bf8*)(&Asm[(wr * 64 + mf * 16 + lr) * LDT + lo * 8]);
#pragma unroll
        for (int nf = 0; nf < 2; ++nf)
            bfr[nf] = *(const bf8*)(&Bsm[(wc * 32 + nf * 16 + lr) * LDT + lo * 8]);
#pragma unroll
        for (int mf = 0; mf < 4; ++mf)
#pragma unroll
            for (int nf = 0; nf < 2; ++nf)
                acc[mf][nf] = __builtin_amdgcn_mfma_f32_16x16x32_bf16(af[mf], bfr[nf], acc[mf][nf], 0, 0, 0);
    }
    // ---- epilogue: D[(lo*4+r)][lr] within each 16x16 fragment ----
#pragma unroll
    for (int mf = 0; mf < 4; ++mf) {
#pragma unroll
        for (int r = 0; r < 4; ++r) {
            int m = m0 + wr * 64 + mf * 16 + lo * 4 + r;
            if (m >= M) continue;
#pragma unroll
            for (int nf = 0; nf < 2; ++nf) {
                int n = n0 + wc * 32 + nf * 16 + lr;
                if (n >= Nc) continue;
                float v = acc[mf][nf][r];
                if (RELU) v = (v >= 0.f) ? v : v * SLOPE;
                C[(size_t)m * Nc + n] = v;
            }
        }
    }
}

// ---------------- fixup for zero-indeg rows: out[row] = rrelu(h[row] @ Wl) ----------------
__global__ __launch_bounds__(256) void fixup_k(const float* __restrict__ h, const float* __restrict__ Wl,
                                               const int* __restrict__ zl, const int* __restrict__ nz,
                                               float* __restrict__ outp) {
    __shared__ float xr[H];
    int nzv = *nz;
    for (int z = blockIdx.x; z < nzv; z += gridDim.x) {
        int row = zl[z];
        if (threadIdx.x < H) xr[threadIdx.x] = h[(size_t)row * H + threadIdx.x];
        __syncthreads();
        if (threadIdx.x < H) {
            float s = 0.f;
            for (int k = 0; k < H; ++k) s += xr[k] * Wl[(size_t)k * H + threadIdx.x];
            outp[(size_t)row * H + threadIdx.x] = (s >= 0.f) ? s : s * SLOPE;
        }
        __syncthreads();
    }
}

// ---------------- entity GRU combine (elementwise over chunk) ----------------
__global__ __launch_bounds__(256) void gru_comb_k(const float* __restrict__ gi, const float* __restrict__ gh,
                                                  const float* __restrict__ bih, const float* __restrict__ bhh,
                                                  const float* __restrict__ h, float* __restrict__ outp,
                                                  int rows, int row0) {
    int idx = blockIdx.x * 256 + threadIdx.x;
    if (idx >= rows * H) return;
    int rl = idx / H;
    int c = idx - rl * H;
    int gr = row0 + rl;
    float ir = gi[(size_t)rl * 600 + c] + bih[c];
    float iz = gi[(size_t)rl * 600 + 200 + c] + bih[200 + c];
    float in_ = gi[(size_t)rl * 600 + 400 + c] + bih[400 + c];
    float hr = gh[(size_t)rl * 600 + c] + bhh[c];
    float hz = gh[(size_t)rl * 600 + 200 + c] + bhh[200 + c];
    float hn = gh[(size_t)rl * 600 + 400 + c] + bhh[400 + c];
    float rr = sigf(ir + hr);
    float zz = sigf(iz + hz);
    float nn = tanhf(in_ + rr * hn);
    outp[(size_t)gr * H + c] = (1.f - zz) * nn + zz * h[(size_t)gr * H + c];
}

// =========================== host orchestration ===========================
extern "C" void kernel_launch(void* const* d_in, const int* in_sizes, int n_in,
                              void* d_out, int out_size, void* d_ws, size_t ws_size,
                              hipStream_t stream) {
    (void)in_sizes; (void)n_in; (void)out_size; (void)ws_size;
    const int* src  = (const int*)d_in[0];
    const int* dst  = (const int*)d_in[1];
    const int* etyp = (const int*)d_in[2];
    const int* rte  = (const int*)d_in[3];
    const int* rseg = (const int*)d_in[4];
    const int* ssrc = (const int*)d_in[5];
    const int* sdst = (const int*)d_in[6];
    const int* setp = (const int*)d_in[7];
    const int* srte = (const int*)d_in[8];
    const int* srseg= (const int*)d_in[9];
    const float* dyn     = (const float*)d_in[10];
    const float* emb_rel = (const float*)d_in[11];
    const float* p_rel   = (const float*)d_in[12];
    const float* Wih1 = (const float*)d_in[13]; const float* Whh1 = (const float*)d_in[14];
    const float* bih1 = (const float*)d_in[15]; const float* bhh1 = (const float*)d_in[16];
    const float* Wih2 = (const float*)d_in[17]; const float* Whh2 = (const float*)d_in[18];
    const float* bih2 = (const float*)d_in[19]; const float* bhh2 = (const float*)d_in[20];
    const float* Wih3 = (const float*)d_in[21]; const float* Whh3 = (const float*)d_in[22];
    const float* bih3 = (const float*)d_in[23]; const float* bhh3 = (const float*)d_in[24];
    const float* Wihe = (const float*)d_in[25]; const float* Whhe = (const float*)d_in[26];
    const float* bihe = (const float*)d_in[27]; const float* bhhe = (const float*)d_in[28];
    const float* Wn  = (const float*)d_in[29];
    const float* Wl  = (const float*)d_in[30];
    const float* We  = (const float*)d_in[31];
    const float* sWn = (const float*)d_in[32];
    const float* sWl = (const float*)d_in[33];
    const float* sWe = (const float*)d_in[34];

    float* out = (float*)d_out;
    const size_t NH = (size_t)N_NODES * H;
    float* relout = out + 3 * NH;

    char* wp = (char*)d_ws;
    auto carve = [&](size_t bytes) -> void* {
        void* p = (void*)wp;
        wp += (bytes + 255) & ~(size_t)255;
        return p;
    };
    float* wsH  = (float*)carve(NH * 4);
    float* wsX  = (float*)carve(NH * 4);  // agg0 during layers, GI/GH during GRU, seg-CSR temp
    float* h0a  = (float*)carve((size_t)R2 * H * 4);
    float* c0b  = (float*)carve((size_t)R2 * H * 4);
    float* xin  = (float*)carve((size_t)R2 * H * 4);
    float* srelA= (float*)carve((size_t)R2 * H * 4);
    float* srelB= (float*)carve((size_t)R2 * H * 4);
    float* sagg = (float*)carve((size_t)R2 * H * 4);
    float* sxin = (float*)carve((size_t)SR * H * 4);
    float* p_h  = (float*)carve((size_t)SR * H * 4);
    float* p_c  = (float*)carve((size_t)SR * H * 4);
    int* ecnt  = (int*)carve((size_t)N_NODES * 4);
    int* eoff  = (int*)carve((size_t)(N_NODES + 1) * 4);
    int* ecur  = (int*)carve((size_t)N_NODES * 4);
    int* esrcp = (int*)carve((size_t)E_EDGES * 4);
    int* eetp  = (int*)carve((size_t)E_EDGES * 4);
    int* zl    = (int*)carve((size_t)N_NODES * 4);
    int* nz    = (int*)carve(4);
    int* rcnt  = (int*)carve((size_t)R2 * 4);
    int* scnt  = (int*)carve((size_t)SR * 4);
    int* sindeg= (int*)carve((size_t)R2 * 4);

    // segment-CSR temporaries live in wsX (free during the seg-mean phase)
    int* rper = (int*)wsX;              // R2E entries
    int* rcsr = (int*)wsX + R2E;        // R2+1
    int* rcur = (int*)wsX + R2E + R2 + 1;  // R2

    // h = l2norm(dynamic_emb)
    l2norm_k<<<N_NODES, 256, 0, stream>>>(dyn, wsH, N_NODES);

    for (int t = 0; t < T_STEPS; ++t) {
        const int* src_t  = src + (size_t)t * E_EDGES;
        const int* dst_t  = dst + (size_t)t * E_EDGES;
        const int* et_t   = etyp + (size_t)t * E_EDGES;
        const int* rte_t  = rte + (size_t)t * R2E;
        const int* rseg_t = rseg + (size_t)t * R2E;
        const int* ssrc_t = ssrc + (size_t)t * SE_EDGES;
        const int* sdst_t = sdst + (size_t)t * SE_EDGES;
        const int* set_t  = setp + (size_t)t * SE_EDGES;
        const int* srte_t = srte + (size_t)t * S2E;
        const int* srseg_t= srseg + (size_t)t * S2E;

        float* hin  = (t == 0) ? wsH : out + (size_t)(t - 1) * NH;
        float* Abuf = (t == 0) ? out + NH : wsH;
        float* Bbuf = out + 2 * NH;
        float* hist = out + (size_t)t * NH;
        float* rel_t = relout + (size_t)t * R2 * H;
        const float* hprev = (t == 0) ? emb_rel : relout + (size_t)(t - 1) * R2 * H;
        const float* cprev = (t == 0) ? xin : c0b;
        const float* php   = (t == 0) ? p_rel : p_h;
        const float* pcp   = (t == 0) ? sxin : p_c;

        // ---- x_input = seg_mean(h[r_to_e], r_seg, R2) via segment CSR ----
        hipMemsetAsync(rcnt, 0, (size_t)R2 * 4, stream);
        seg_cnt_k<<<64, 256, 0, stream>>>(rseg_t, R2E, rcnt, R2);
        scan_k<<<1, 1024, 0, stream>>>(rcnt, rcsr, rcur, R2);
        seg_scatter_k<<<(R2E + 255) / 256, 256, 0, stream>>>(rseg_t, rte_t, rcur, rper, R2E);
        seg_mean_csr_k<<<R2, 256, 0, stream>>>(hin, rper, rcsr, xin, R2);
        // ---- LSTM1 ----
        lstm_k<<<R2, 256, 0, stream>>>(emb_rel, xin, hprev, cprev, Wih1, Whh1, bih1, bhh1, h0a, c0b, R2);
        // ---- sx = seg_mean(h_0[s_r_to_e], s_r_seg, SR) (small; LDS path) ----
        hipMemsetAsync(sxin, 0, (size_t)SR * H * 4, stream);
        hipMemsetAsync(scnt, 0, (size_t)SR * 4, stream);
        seg_cnt_k<<<8, 256, 0, stream>>>(srseg_t, S2E, scnt, SR);
        seg_acc_k<<<16 * 8, 256, 0, stream>>>(h0a, srte_t, srseg_t, S2E, sxin, SR);
        seg_div_k<<<(SR * H + 255) / 256, 256, 0, stream>>>(sxin, scnt, SR);
        // ---- LSTM2 ----
        lstm_k<<<SR, 256, 0, stream>>>(p_rel, sxin, php, pcp, Wih2, Whh2, bih2, bhh2, p_h, p_c, SR);
        // ---- super RGCN (2 layers) ----
        hipMemsetAsync(sindeg, 0, (size_t)R2 * 4, stream);
        cnt_k<<<(SE_EDGES + 255) / 256, 256, 0, stream>>>(sdst_t, SE_EDGES, sindeg);
        hipMemsetAsync(sagg, 0, (size_t)R2 * H * 4, stream);
        sup_agg_k<<<SE_EDGES, 256, 0, stream>>>(h0a, p_h, ssrc_t, sdst_t, set_t, sagg, SE_EDGES);
        sup_comb_k<<<R2, 256, 0, stream>>>(sagg, h0a, sWn, sWe, sWl, sindeg, srelA);
        hipMemsetAsync(sagg, 0, (size_t)R2 * H * 4, stream);
        sup_agg_k<<<SE_EDGES, 256, 0, stream>>>(srelA, p_h, ssrc_t, sdst_t, set_t, sagg, SE_EDGES);
        sup_comb_k<<<R2, 256, 0, stream>>>(sagg, srelA, sWn + H * H, sWe + H * H, sWl + H * H, sindeg, srelB);
        l2norm_k<<<R2, 256, 0, stream>>>(srelB, srelB, R2);
        // ---- rel GRU -> rel_embs[t] ----
        gru_small_k<<<R2, 256, 0, stream>>>(srelB, h0a, Wih3, Whh3, bih3, bhh3, rel_t, R2);

        // ---- entity CSR build ----
        hipMemsetAsync(ecnt, 0, (size_t)N_NODES * 4, stream);
        hipMemsetAsync(nz, 0, 4, stream);
        cnt_k<<<(E_EDGES + 255) / 256, 256, 0, stream>>>(dst_t, E_EDGES, ecnt);
        scan_k<<<1, 1024, 0, stream>>>(ecnt, eoff, ecur, N_NODES);
        scatter_k<<<(E_EDGES + 255) / 256, 256, 0, stream>>>(dst_t, src_t, et_t, ecur, esrcp, eetp, E_EDGES);
        zlist_k<<<(N_NODES + 255) / 256, 256, 0, stream>>>(ecnt, zl, nz, N_NODES);

        dim3 gl((N_NODES + GBM - 1) / GBM, (H + GBN - 1) / GBN);
        // ---- entity layer 0: rrelu(agg@Wn + h@We), fixup zero-indeg rows ----
        ent_agg_k<<<(N_NODES + 3) / 4, 256, 0, stream>>>(hin, rel_t, eoff, esrcp, eetp, wsX, N_NODES);
        gemm_bf16_k<0, 1, 1><<<gl, 256, 0, stream>>>(wsX, hin, Wn, We, Abuf, N_NODES, H);
        fixup_k<<<2048, 256, 0, stream>>>(hin, Wl, zl, nz, Abuf);
        // ---- entity layer 1 ----
        ent_agg_k<<<(N_NODES + 3) / 4, 256, 0, stream>>>(Abuf, rel_t, eoff, esrcp, eetp, wsX, N_NODES);
        gemm_bf16_k<0, 1, 1><<<gl, 256, 0, stream>>>(wsX, Abuf, Wn + H * H, We + H * H, Bbuf, N_NODES, H);
        fixup_k<<<2048, 256, 0, stream>>>(Abuf, Wl + H * H, zl, nz, Bbuf);
        l2norm_k<<<N_NODES, 256, 0, stream>>>(Bbuf, Bbuf, N_NODES);

        // ---- entity GRU (chunked GI/GH bf16 GEMMs + combine) ----
        const int CHUNK = 16000;  // CHUNK*1200 floats fits in wsX
        for (int r0 = 0; r0 < N_NODES; r0 += CHUNK) {
            int rows = (N_NODES - r0 < CHUNK) ? (N_NODES - r0) : CHUNK;
            float* GI = wsX;
            float* GH = wsX + (size_t)CHUNK * 600;
            dim3 gg((rows + GBM - 1) / GBM, (600 + GBN - 1) / GBN);
            gemm_bf16_k<1, 0, 0><<<gg, 256, 0, stream>>>(Bbuf + (size_t)r0 * H, nullptr, Wihe, nullptr, GI, rows, 600);
            gemm_bf16_k<1, 0, 0><<<gg, 256, 0, stream>>>(hin + (size_t)r0 * H, nullptr, Whhe, nullptr, GH, rows, 600);
            gru_comb_k<<<(rows * H + 255) / 256, 256, 0, stream>>>(GI, GH, bihe, bhhe, hin, hist, rows, r0);
        }
        l2norm_k<<<N_NODES, 256, 0, stream>>>(hist, hist, N_NODES);
    }
}

// Round 3
// 6149.928 us; speedup vs baseline: 1.6882x; 1.1079x over previous
//
#include <hip/hip_runtime.h>
#include <math.h>

#define N_NODES 100000
#define H 200
#define R2 500
#define T_STEPS 3
#define E_EDGES 300000
#define R2E 400000
#define SE_EDGES 4000
#define SR 8
#define S2E 8000
#define SLOPE 0.22916666666666666f

static __device__ __forceinline__ float sigf(float x) { return 1.f / (1.f + expf(-x)); }

// ---------------- l2 normalize rows (wave per row, float4) ----------------
__global__ __launch_bounds__(256) void l2norm_k(const float* __restrict__ src,
                                                float* __restrict__ dst, int rows) {
    int wave = threadIdx.x >> 6, lane = threadIdx.x & 63;
    int r = blockIdx.x * 4 + wave;
    if (r >= rows) return;
    float4 v = make_float4(0.f, 0.f, 0.f, 0.f);
    if (lane < 50) v = *(const float4*)(src + (size_t)r * H + lane * 4);
    float s = v.x * v.x + v.y * v.y + v.z * v.z + v.w * v.w;
    for (int o = 32; o > 0; o >>= 1) s += __shfl_down(s, o);
    float rn = 1.f / fmaxf(sqrtf(__shfl(s, 0)), 1e-12f);
    if (lane < 50) {
        float4 o4 = make_float4(v.x * rn, v.y * rn, v.z * rn, v.w * rn);
        *(float4*)(dst + (size_t)r * H + lane * 4) = o4;
    }
}

// ---------------- generic counting ----------------
__global__ void cnt_k(const int* __restrict__ d, int n, int* __restrict__ cnt) {
    int i = blockIdx.x * blockDim.x + threadIdx.x;
    if (i < n) atomicAdd(&cnt[d[i]], 1);
}

// ---------------- segment counts with LDS hierarchy ----------------
__global__ __launch_bounds__(256) void seg_cnt_k(const int* __restrict__ seg, int n,
                                                 int* __restrict__ cnt, int nseg) {
    __shared__ int lc[500];
    for (int i = threadIdx.x; i < nseg; i += 256) lc[i] = 0;
    __syncthreads();
    int chunk = (n + gridDim.x - 1) / gridDim.x;
    int beg = blockIdx.x * chunk;
    int end = beg + chunk; if (end > n) end = n;
    for (int i = beg + threadIdx.x; i < end; i += 256) atomicAdd(&lc[seg[i]], 1);
    __syncthreads();
    for (int i = threadIdx.x; i < nseg; i += 256) if (lc[i]) atomicAdd(&cnt[i], lc[i]);
}

// ---------------- small segment sum (SR path), LDS col-chunked ----------------
#define SEG_CW 25
__global__ __launch_bounds__(256) void seg_acc_k(const float* __restrict__ hsrc,
                                                 const int* __restrict__ idx,
                                                 const int* __restrict__ seg, int n,
                                                 float* __restrict__ acc, int nseg) {
    __shared__ float lacc[500 * SEG_CW];
    int cg = blockIdx.x & 7;
    int pb = blockIdx.x >> 3;
    int NPB = gridDim.x >> 3;
    int t = threadIdx.x;
    for (int i = t; i < nseg * SEG_CW; i += 256) lacc[i] = 0.f;
    __syncthreads();
    int chunk = (n + NPB - 1) / NPB;
    int beg = pb * chunk;
    int end = beg + chunk; if (end > n) end = n;
    if (t < 250) {
        int il = t / SEG_CW;
        int c = t - il * SEG_CW;
        int col = cg * SEG_CW + c;
        for (int i = beg + il; i < end; i += 10) {
            int r = seg[i];
            int e = idx[i];
            atomicAdd(&lacc[r * SEG_CW + c], hsrc[(size_t)e * H + col]);
        }
    }
    __syncthreads();
    for (int i = t; i < nseg * SEG_CW; i += 256) {
        int r = i / SEG_CW, c = i - (i / SEG_CW) * SEG_CW;
        atomicAdd(&acc[(size_t)r * H + cg * SEG_CW + c], lacc[i]);
    }
}

__global__ void seg_div_k(float* __restrict__ acc, const int* __restrict__ cnt, int rows) {
    int i = blockIdx.x * blockDim.x + threadIdx.x;
    if (i < rows * H) {
        int c = cnt[i / H];
        acc[i] /= (float)(c > 0 ? c : 1);
    }
}

// ---------------- segment permutation scatter ----------------
__global__ void seg_scatter_k(const int* __restrict__ seg, const int* __restrict__ val,
                              int* __restrict__ cur, int* __restrict__ outp, int n) {
    int i = blockIdx.x * blockDim.x + threadIdx.x;
    if (i < n) {
        int p = atomicAdd(&cur[seg[i]], 1);
        outp[p] = val[i];
    }
}

// ---------------- CSR segment mean: one block per segment, coalesced rows ----------------
__global__ __launch_bounds__(256) void seg_mean_csr_k(const float* __restrict__ h,
                                                      const int* __restrict__ per,
                                                      const int* __restrict__ off,
                                                      float* __restrict__ xout, int nseg) {
    int r = blockIdx.x;
    if (r >= nseg) return;
    int t = threadIdx.x;
    int beg = off[r], end = off[r + 1];
    if (t >= H) return;
    float acc = 0.f;
    int i = beg;
    for (; i + 4 <= end; i += 4) {
        int e0 = per[i], e1 = per[i + 1], e2 = per[i + 2], e3 = per[i + 3];
        float v0 = h[(size_t)e0 * H + t];
        float v1 = h[(size_t)e1 * H + t];
        float v2 = h[(size_t)e2 * H + t];
        float v3 = h[(size_t)e3 * H + t];
        acc += v0 + v1 + v2 + v3;
    }
    for (; i < end; ++i) acc += h[(size_t)per[i] * H + t];
    float c = (float)(end - beg);
    xout[(size_t)r * H + t] = acc / fmaxf(c, 1.f);
}

// ---------------- fused LSTM cell + l2norm of h and c ----------------
__global__ __launch_bounds__(256) void lstm_k(const float* __restrict__ x1, const float* __restrict__ x2,
                                              const float* __restrict__ hprev, const float* __restrict__ cprev,
                                              const float* __restrict__ Wih, const float* __restrict__ Whh,
                                              const float* __restrict__ bih, const float* __restrict__ bhh,
                                              float* __restrict__ hout, float* __restrict__ cout, int rows) {
    int r = blockIdx.x;
    if (r >= rows) return;
    __shared__ float xb[2 * H], hb[H], gb[4 * H], hv[H], cv[H];
    __shared__ float red[8];
    int t = threadIdx.x;
    for (int i = t; i < 2 * H; i += 256)
        xb[i] = (i < H) ? x1[(size_t)r * H + i] : x2[(size_t)r * H + i - H];
    if (t < H) hb[t] = hprev[(size_t)r * H + t];
    __syncthreads();
    for (int j = t; j < 4 * H; j += 256) {
        float s = bih[j] + bhh[j];
        const float* wi = Wih + (size_t)j * 2 * H;
        for (int k = 0; k < 2 * H; ++k) s += xb[k] * wi[k];
        const float* wh = Whh + (size_t)j * H;
        for (int k = 0; k < H; ++k) s += hb[k] * wh[k];
        gb[j] = s;
    }
    __syncthreads();
    if (t < H) {
        float ig = sigf(gb[t]);
        float fg = sigf(gb[H + t]);
        float gg = tanhf(gb[2 * H + t]);
        float og = sigf(gb[3 * H + t]);
        float c2 = fg * cprev[(size_t)r * H + t] + ig * gg;
        cv[t] = c2;
        hv[t] = og * tanhf(c2);
    }
    __syncthreads();
    float sh = 0.f, sc = 0.f;
    if (t < H) { sh = hv[t] * hv[t]; sc = cv[t] * cv[t]; }
    for (int o = 32; o > 0; o >>= 1) { sh += __shfl_down(sh, o); sc += __shfl_down(sc, o); }
    if ((t & 63) == 0) { red[t >> 6] = sh; red[4 + (t >> 6)] = sc; }
    __syncthreads();
    if (t == 0) {
        red[0] = 1.f / fmaxf(sqrtf(red[0] + red[1] + red[2] + red[3]), 1e-12f);
        red[4] = 1.f / fmaxf(sqrtf(red[4] + red[5] + red[6] + red[7]), 1e-12f);
    }
    __syncthreads();
    if (t < H) {
        hout[(size_t)r * H + t] = hv[t] * red[0];
        cout[(size_t)r * H + t] = cv[t] * red[4];
    }
}

// ---------------- fused small GRU + l2norm ----------------
__global__ __launch_bounds__(256) void gru_small_k(const float* __restrict__ x, const float* __restrict__ h,
                                                   const float* __restrict__ Wih, const float* __restrict__ Whh,
                                                   const float* __restrict__ bih, const float* __restrict__ bhh,
                                                   float* __restrict__ outp, int rows) {
    int r = blockIdx.x;
    if (r >= rows) return;
    __shared__ float xb[H], hb[H], gi[3 * H], gh[3 * H], ov[H];
    __shared__ float red[4];
    int t = threadIdx.x;
    if (t < H) { xb[t] = x[(size_t)r * H + t]; hb[t] = h[(size_t)r * H + t]; }
    __syncthreads();
    for (int j = t; j < 3 * H; j += 256) {
        float si = bih[j], sh2 = bhh[j];
        const float* wi = Wih + (size_t)j * H;
        const float* wh = Whh + (size_t)j * H;
        for (int k = 0; k < H; ++k) { si += xb[k] * wi[k]; sh2 += hb[k] * wh[k]; }
        gi[j] = si; gh[j] = sh2;
    }
    __syncthreads();
    if (t < H) {
        float rr = sigf(gi[t] + gh[t]);
        float zz = sigf(gi[H + t] + gh[H + t]);
        float nn = tanhf(gi[2 * H + t] + rr * gh[2 * H + t]);
        ov[t] = (1.f - zz) * nn + zz * hb[t];
    }
    __syncthreads();
    float s = (t < H) ? ov[t] * ov[t] : 0.f;
    for (int o = 32; o > 0; o >>= 1) s += __shfl_down(s, o);
    if ((t & 63) == 0) red[t >> 6] = s;
    __syncthreads();
    if (t == 0) red[0] = 1.f / fmaxf(sqrtf(red[0] + red[1] + red[2] + red[3]), 1e-12f);
    __syncthreads();
    if (t < H) outp[(size_t)r * H + t] = ov[t] * red[0];
}

// ---------------- super-graph raw message aggregation ----------------
__global__ __launch_bounds__(256) void sup_agg_k(const float* __restrict__ cur, const float* __restrict__ prel,
                                                 const int* __restrict__ ss, const int* __restrict__ sd,
                                                 const int* __restrict__ se, float* __restrict__ sagg, int nE) {
    int e = blockIdx.x;
    if (e >= nE) return;
    int t = threadIdx.x;
    if (t < H) {
        int s = ss[e], d = sd[e], et = se[e];
        float v = cur[(size_t)s * H + t] + prel[(size_t)et * H + t];
        atomicAdd(&sagg[(size_t)d * H + t], v);
    }
}

// ---------------- super-graph combine: rrelu(agg@Wn + cur@Wsel) ----------------
__global__ __launch_bounds__(256) void sup_comb_k(const float* __restrict__ agg, const float* __restrict__ cur,
                                                  const float* __restrict__ Wn, const float* __restrict__ We,
                                                  const float* __restrict__ Wl, const int* __restrict__ indeg,
                                                  float* __restrict__ outp) {
    int r = blockIdx.x;
    __shared__ float ar[H], cr[H];
    int t = threadIdx.x;
    if (t < H) { ar[t] = agg[(size_t)r * H + t]; cr[t] = cur[(size_t)r * H + t]; }
    __syncthreads();
    const float* W2 = (indeg[r] > 0) ? We : Wl;
    if (t < H) {
        float s = 0.f;
        for (int k = 0; k < H; ++k) s += ar[k] * Wn[(size_t)k * H + t] + cr[k] * W2[(size_t)k * H + t];
        outp[(size_t)r * H + t] = (s >= 0.f) ? s : s * SLOPE;
    }
}

// ---------------- CSR scan (single block) ----------------
__global__ __launch_bounds__(1024) void scan_k(const int* __restrict__ cnt, int* __restrict__ off,
                                               int* __restrict__ cur, int n) {
    __shared__ int part[1024];
    int tid = threadIdx.x;
    int per = (n + 1023) / 1024;
    int s0 = tid * per;
    int e0 = s0 + per; if (e0 > n) e0 = n;
    int sum = 0;
    for (int i = s0; i < e0; ++i) sum += cnt[i];
    part[tid] = sum;
    __syncthreads();
    for (int d = 1; d < 1024; d <<= 1) {
        int v = (tid >= d) ? part[tid - d] : 0;
        __syncthreads();
        part[tid] += v;
        __syncthreads();
    }
    int excl = (tid == 0) ? 0 : part[tid - 1];
    for (int i = s0; i < e0; ++i) { off[i] = excl; cur[i] = excl; excl += cnt[i]; }
    if (tid == 1023) off[n] = excl;
}

__global__ void scatter_k(const int* __restrict__ dst, const int* __restrict__ src,
                          const int* __restrict__ et, int* __restrict__ cur,
                          int* __restrict__ psrc, int* __restrict__ pet, int nE) {
    int e = blockIdx.x * blockDim.x + threadIdx.x;
    if (e < nE) {
        int p = atomicAdd(&cur[dst[e]], 1);
        psrc[p] = src[e];
        pet[p] = et[e];
    }
}

__global__ void zlist_k(const int* __restrict__ cnt, int* __restrict__ zl, int* __restrict__ nz, int n) {
    int v = blockIdx.x * blockDim.x + threadIdx.x;
    if (v < n && cnt[v] == 0) {
        int p = atomicAdd(nz, 1);
        zl[p] = v;
    }
}

// ---------------- entity raw message aggregation via CSR (wave per dst) ----------------
__global__ __launch_bounds__(256) void ent_agg_k(const float* __restrict__ cur, const float* __restrict__ rel,
                                                 const int* __restrict__ eoff, const int* __restrict__ esrc,
                                                 const int* __restrict__ eet, float* __restrict__ agg, int n) {
    int wave = threadIdx.x >> 6, lane = threadIdx.x & 63;
    int v = blockIdx.x * 4 + wave;
    if (v >= n) return;
    float a0 = 0.f, a1 = 0.f, a2 = 0.f, a3 = 0.f;
    int c3 = lane + 192;
    int beg = eoff[v], end = eoff[v + 1];
    for (int i = beg; i < end; ++i) {
        const float* hr = cur + (size_t)esrc[i] * H;
        const float* rr = rel + (size_t)eet[i] * H;
        a0 += hr[lane] + rr[lane];
        a1 += hr[lane + 64] + rr[lane + 64];
        a2 += hr[lane + 128] + rr[lane + 128];
        if (c3 < H) a3 += hr[c3] + rr[c3];
    }
    float* o = agg + (size_t)v * H;
    o[lane] = a0; o[lane + 64] = a1; o[lane + 128] = a2;
    if (c3 < H) o[c3] = a3;
}

// ---------------- bf16 MFMA GEMM (N-blocks fast-varying for L2/L3 A reuse) ----------------
#define GBM 128
#define GBN 64
#define LDT 40  // LDS row stride in bf16 elems

template <int BT, int DUAL, int RELU>
__global__ __launch_bounds__(256, 2) void gemm_bf16_k(const float* __restrict__ A1, const float* __restrict__ A2,
                                                      const float* __restrict__ B1, const float* __restrict__ B2,
                                                      float* __restrict__ C, int M, int Nc) {
    typedef __bf16 bf8 __attribute__((ext_vector_type(8)));
    typedef __bf16 bf4 __attribute__((ext_vector_type(4)));
    typedef float f32x4 __attribute__((ext_vector_type(4)));
    __shared__ __bf16 Asm[GBM * LDT];
    __shared__ __bf16 Bsm[GBN * LDT];
    const int tid = threadIdx.x;
    const int m0 = blockIdx.y * GBM;   // row panel: slow-varying
    const int n0 = blockIdx.x * GBN;   // col block: fast-varying (L2/L3 reuse of A)
    const int w = tid >> 6, lane = tid & 63;
    const int wr = w >> 1, wc = w & 1;
    const int lr = lane & 15, lo = lane >> 4;
    f32x4 acc[4][2];
#pragma unroll
    for (int i = 0; i < 4; ++i)
#pragma unroll
        for (int j = 0; j < 2; ++j)
#pragma unroll
            for (int e = 0; e < 4; ++e) acc[i][j][e] = 0.f;

    const int NT = DUAL ? 14 : 7;
    for (int kt = 0; kt < NT; ++kt) {
        const float* Ap = (DUAL && kt >= 7) ? A2 : A1;
        const float* Bp = (DUAL && kt >= 7) ? B2 : B1;
        const int k0 = (DUAL && kt >= 7) ? (kt - 7) * 32 : kt * 32;
        if (kt) __syncthreads();
        {
            int row = tid >> 1, half = tid & 1;
            int m = m0 + row;
#pragma unroll
            for (int j = 0; j < 4; ++j) {
                int k = k0 + half * 16 + j * 4;
                float4 v = make_float4(0.f, 0.f, 0.f, 0.f);
                if (m < M && k < 200) v = *(const float4*)(Ap + (size_t)m * 200 + k);
                bf4 b;
                b[0] = (__bf16)v.x; b[1] = (__bf16)v.y; b[2] = (__bf16)v.z; b[3] = (__bf16)v.w;
                *(bf4*)(&Asm[row * LDT + half * 16 + j * 4]) = b;
            }
        }
        if (BT) {
            int row = tid >> 2, q = tid & 3;
            int n = n0 + row;
#pragma unroll
            for (int j = 0; j < 2; ++j) {
                int k = k0 + q * 8 + j * 4;
                float4 v = make_float4(0.f, 0.f, 0.f, 0.f);
                if (n < Nc && k < 200) v = *(const float4*)(Bp + (size_t)n * 200 + k);
                bf4 b;
                b[0] = (__bf16)v.x; b[1] = (__bf16)v.y; b[2] = (__bf16)v.z; b[3] = (__bf16)v.w;
                *(bf4*)(&Bsm[row * LDT + q * 8 + j * 4]) = b;
            }
        } else {
            int kl = tid >> 3, nb = (tid & 7) * 8;
#pragma unroll
            for (int j = 0; j < 8; ++j) {
                int nl = nb + j;
                int n = n0 + nl, k = k0 + kl;
                float v = (n < Nc && k < 200) ? Bp[(size_t)k * Nc + n] : 0.f;
                Bsm[nl * LDT + kl] = (__bf16)v;
            }
        }
        __syncthreads();
        bf8 af[4], bfr[2];
#pragma unroll
        for (int mf = 0; mf < 4; ++mf)
            af[mf] = *(const bf8*)(&Asm[(wr * 64 + mf * 16 + lr) * LDT + lo * 8]);
#pragma unroll
        for (int nf = 0; nf < 2; ++nf)
            bfr[nf] = *(const bf8*)(&Bsm[(wc * 32 + nf * 16 + lr) * LDT + lo * 8]);
#pragma unroll
        for (int mf = 0; mf < 4; ++mf)
#pragma unroll
            for (int nf = 0; nf < 2; ++nf)
                acc[mf][nf] = __builtin_amdgcn_mfma_f32_16x16x32_bf16(af[mf], bfr[nf], acc[mf][nf], 0, 0, 0);
    }
#pragma unroll
    for (int mf = 0; mf < 4; ++mf) {
#pragma unroll
        for (int r = 0; r < 4; ++r) {
            int m = m0 + wr * 64 + mf * 16 + lo * 4 + r;
            if (m >= M) continue;
#pragma unroll
            for (int nf = 0; nf < 2; ++nf) {
                int n = n0 + wc * 32 + nf * 16 + lr;
                if (n >= Nc) continue;
                float v = acc[mf][nf][r];
                if (RELU) v = (v >= 0.f) ? v : v * SLOPE;
                C[(size_t)m * Nc + n] = v;
            }
        }
    }
}

// ---------------- fully fused entity GRU (bf16 MFMA, gates in registers) ----------------
// Block tile: 64 rows x 64 out-cols. Computes 6 sub-GEMMs (x@Wih^T r/z/n, h@Whh^T r/z/n)
// and applies GRU nonlinearity in the epilogue. Out must not alias X or Hs.
__global__ __launch_bounds__(256, 2) void gru_fused_k(const float* __restrict__ X, const float* __restrict__ Hs,
                                                      const float* __restrict__ Wih, const float* __restrict__ Whh,
                                                      const float* __restrict__ bih, const float* __restrict__ bhh,
                                                      float* __restrict__ Out, int M) {
    typedef __bf16 bf8 __attribute__((ext_vector_type(8)));
    typedef __bf16 bf4 __attribute__((ext_vector_type(4)));
    typedef float f32x4 __attribute__((ext_vector_type(4)));
    __shared__ __bf16 Xs[64 * LDT];
    __shared__ __bf16 Hsm[64 * LDT];
    __shared__ __bf16 Wsm[6][64 * LDT];
    const int tid = threadIdx.x;
    const int n0 = blockIdx.x * 64;   // out-col block (fast-varying -> X/H panels L2-hot)
    const int m0 = blockIdx.y * 64;
    const int w = tid >> 6, lane = tid & 63;
    const int wr = w >> 1, wc = w & 1;
    const int lr = lane & 15, lo = lane >> 4;
    const int row = tid >> 2, q = tid & 3;
    f32x4 acc[6][2][2];
#pragma unroll
    for (int s = 0; s < 6; ++s)
#pragma unroll
        for (int i = 0; i < 2; ++i)
#pragma unroll
            for (int j = 0; j < 2; ++j)
#pragma unroll
                for (int e = 0; e < 4; ++e) acc[s][i][j][e] = 0.f;

    for (int kt = 0; kt < 7; ++kt) {
        const int k0 = kt * 32;
        if (kt) __syncthreads();
        {
            int m = m0 + row;
#pragma unroll
            for (int j = 0; j < 2; ++j) {
                int k = k0 + q * 8 + j * 4;
                float4 vx = make_float4(0.f, 0.f, 0.f, 0.f);
                float4 vh = make_float4(0.f, 0.f, 0.f, 0.f);
                if (m < M && k < 200) {
                    vx = *(const float4*)(X + (size_t)m * 200 + k);
                    vh = *(const float4*)(Hs + (size_t)m * 200 + k);
                }
                bf4 bx, bh;
                bx[0] = (__bf16)vx.x; bx[1] = (__bf16)vx.y; bx[2] = (__bf16)vx.z; bx[3] = (__bf16)vx.w;
                bh[0] = (__bf16)vh.x; bh[1] = (__bf16)vh.y; bh[2] = (__bf16)vh.z; bh[3] = (__bf16)vh.w;
                *(bf4*)(&Xs[row * LDT + q * 8 + j * 4]) = bx;
                *(bf4*)(&Hsm[row * LDT + q * 8 + j * 4]) = bh;
            }
        }
#pragma unroll
        for (int s = 0; s < 6; ++s) {
            const float* Wp = (s < 3) ? Wih : Whh;
            int sb = (s % 3) * 200;
            int c = n0 + row;
#pragma unroll
            for (int j = 0; j < 2; ++j) {
                int k = k0 + q * 8 + j * 4;
                float4 v = make_float4(0.f, 0.f, 0.f, 0.f);
                if (c < 200 && k < 200) v = *(const float4*)(Wp + (size_t)(sb + c) * 200 + k);
                bf4 b;
                b[0] = (__bf16)v.x; b[1] = (__bf16)v.y; b[2] = (__bf16)v.z; b[3] = (__bf16)v.w;
                *(bf4*)(&Wsm[s][row * LDT + q * 8 + j * 4]) = b;
            }
        }
        __syncthreads();
        bf8 xa[2], ha[2], wb[6][2];
#pragma unroll
        for (int mf = 0; mf < 2; ++mf) {
            xa[mf] = *(const bf8*)(&Xs[(wr * 32 + mf * 16 + lr) * LDT + lo * 8]);
            ha[mf] = *(const bf8*)(&Hsm[(wr * 32 + mf * 16 + lr) * LDT + lo * 8]);
        }
#pragma unroll
        for (int s = 0; s < 6; ++s)
#pragma unroll
            for (int nf = 0; nf < 2; ++nf)
                wb[s][nf] = *(const bf8*)(&Wsm[s][(wc * 32 + nf * 16 + lr) * LDT + lo * 8]);
#pragma unroll
        for (int s = 0; s < 6; ++s)
#pragma unroll
            for (int mf = 0; mf < 2; ++mf) {
                bf8 a = (s < 3) ? xa[mf] : ha[mf];
#pragma unroll
                for (int nf = 0; nf < 2; ++nf)
                    acc[s][mf][nf] = __builtin_amdgcn_mfma_f32_16x16x32_bf16(a, wb[s][nf], acc[s][mf][nf], 0, 0, 0);
            }
    }
    // epilogue: GRU nonlinearity
#pragma unroll
    for (int mf = 0; mf < 2; ++mf)
#pragma unroll
        for (int nf = 0; nf < 2; ++nf) {
            int c = n0 + wc * 32 + nf * 16 + lr;
            if (c >= 200) continue;
            float b0 = bih[c], b1 = bih[200 + c], b2 = bih[400 + c];
            float b3 = bhh[c], b4 = bhh[200 + c], b5 = bhh[400 + c];
#pragma unroll
            for (int r = 0; r < 4; ++r) {
                int m = m0 + wr * 32 + mf * 16 + lo * 4 + r;
                if (m >= M) continue;
                float ir = acc[0][mf][nf][r] + b0;
                float iz = acc[1][mf][nf][r] + b1;
                float in_ = acc[2][mf][nf][r] + b2;
                float hr = acc[3][mf][nf][r] + b3;
                float hz = acc[4][mf][nf][r] + b4;
                float hn = acc[5][mf][nf][r] + b5;
                float rr = sigf(ir + hr);
                float zz = sigf(iz + hz);
                float nn = tanhf(in_ + rr * hn);
                Out[(size_t)m * 200 + c] = (1.f - zz) * nn + zz * Hs[(size_t)m * 200 + c];
            }
        }
}

// ---------------- fixup for zero-indeg rows: out[row] = rrelu(h[row] @ Wl) ----------------
__global__ __launch_bounds__(256) void fixup_k(const float* __restrict__ h, const float* __restrict__ Wl,
                                               const int* __restrict__ zl, const int* __restrict__ nz,
                                               float* __restrict__ outp) {
    __shared__ float xr[H];
    int nzv = *nz;
    for (int z = blockIdx.x; z < nzv; z += gridDim.x) {
        int row = zl[z];
        if (threadIdx.x < H) xr[threadIdx.x] = h[(size_t)row * H + threadIdx.x];
        __syncthreads();
        if (threadIdx.x < H) {
            float s = 0.f;
            for (int k = 0; k < H; ++k) s += xr[k] * Wl[(size_t)k * H + threadIdx.x];
            outp[(size_t)row * H + threadIdx.x] = (s >= 0.f) ? s : s * SLOPE;
        }
        __syncthreads();
    }
}

// =========================== host orchestration ===========================
extern "C" void kernel_launch(void* const* d_in, const int* in_sizes, int n_in,
                              void* d_out, int out_size, void* d_ws, size_t ws_size,
                              hipStream_t stream) {
    (void)in_sizes; (void)n_in; (void)out_size; (void)ws_size;
    const int* src  = (const int*)d_in[0];
    const int* dst  = (const int*)d_in[1];
    const int* etyp = (const int*)d_in[2];
    const int* rte  = (const int*)d_in[3];
    const int* rseg = (const int*)d_in[4];
    const int* ssrc = (const int*)d_in[5];
    const int* sdst = (const int*)d_in[6];
    const int* setp = (const int*)d_in[7];
    const int* srte = (const int*)d_in[8];
    const int* srseg= (const int*)d_in[9];
    const float* dyn     = (const float*)d_in[10];
    const float* emb_rel = (const float*)d_in[11];
    const float* p_rel   = (const float*)d_in[12];
    const float* Wih1 = (const float*)d_in[13]; const float* Whh1 = (const float*)d_in[14];
    const float* bih1 = (const float*)d_in[15]; const float* bhh1 = (const float*)d_in[16];
    const float* Wih2 = (const float*)d_in[17]; const float* Whh2 = (const float*)d_in[18];
    const float* bih2 = (const float*)d_in[19]; const float* bhh2 = (const float*)d_in[20];
    const float* Wih3 = (const float*)d_in[21]; const float* Whh3 = (const float*)d_in[22];
    const float* bih3 = (const float*)d_in[23]; const float* bhh3 = (const float*)d_in[24];
    const float* Wihe = (const float*)d_in[25]; const float* Whhe = (const float*)d_in[26];
    const float* bihe = (const float*)d_in[27]; const float* bhhe = (const float*)d_in[28];
    const float* Wn  = (const float*)d_in[29];
    const float* Wl  = (const float*)d_in[30];
    const float* We  = (const float*)d_in[31];
    const float* sWn = (const float*)d_in[32];
    const float* sWl = (const float*)d_in[33];
    const float* sWe = (const float*)d_in[34];

    float* out = (float*)d_out;
    const size_t NH = (size_t)N_NODES * H;
    float* relout = out + 3 * NH;

    char* wp = (char*)d_ws;
    auto carve = [&](size_t bytes) -> void* {
        void* p = (void*)wp;
        wp += (bytes + 255) & ~(size_t)255;
        return p;
    };
    float* wsH  = (float*)carve(NH * 4);
    float* wsX  = (float*)carve(NH * 4);
    float* h0a  = (float*)carve((size_t)R2 * H * 4);
    float* c0b  = (float*)carve((size_t)R2 * H * 4);
    float* xin  = (float*)carve((size_t)R2 * H * 4);
    float* srelA= (float*)carve((size_t)R2 * H * 4);
    float* srelB= (float*)carve((size_t)R2 * H * 4);
    float* sagg = (float*)carve((size_t)R2 * H * 4);
    float* sxin = (float*)carve((size_t)SR * H * 4);
    float* p_h  = (float*)carve((size_t)SR * H * 4);
    float* p_c  = (float*)carve((size_t)SR * H * 4);
    int* ecnt  = (int*)carve((size_t)N_NODES * 4);
    int* eoff  = (int*)carve((size_t)(N_NODES + 1) * 4);
    int* ecur  = (int*)carve((size_t)N_NODES * 4);
    int* esrcp = (int*)carve((size_t)E_EDGES * 4);
    int* eetp  = (int*)carve((size_t)E_EDGES * 4);
    int* zl    = (int*)carve((size_t)N_NODES * 4);
    int* nz    = (int*)carve(4);
    int* rcnt  = (int*)carve((size_t)R2 * 4);
    int* scnt  = (int*)carve((size_t)SR * 4);
    int* sindeg= (int*)carve((size_t)R2 * 4);

    int* rper = (int*)wsX;
    int* rcsr = (int*)wsX + R2E;
    int* rcur = (int*)wsX + R2E + R2 + 1;

    l2norm_k<<<(N_NODES + 3) / 4, 256, 0, stream>>>(dyn, wsH, N_NODES);

    for (int t = 0; t < T_STEPS; ++t) {
        const int* src_t  = src + (size_t)t * E_EDGES;
        const int* dst_t  = dst + (size_t)t * E_EDGES;
        const int* et_t   = etyp + (size_t)t * E_EDGES;
        const int* rte_t  = rte + (size_t)t * R2E;
        const int* rseg_t = rseg + (size_t)t * R2E;
        const int* ssrc_t = ssrc + (size_t)t * SE_EDGES;
        const int* sdst_t = sdst + (size_t)t * SE_EDGES;
        const int* set_t  = setp + (size_t)t * SE_EDGES;
        const int* srte_t = srte + (size_t)t * S2E;
        const int* srseg_t= srseg + (size_t)t * S2E;

        float* hin  = (t == 0) ? wsH : out + (size_t)(t - 1) * NH;
        float* Abuf = (t == 0) ? out + NH : wsH;
        float* Bbuf = out + 2 * NH;
        float* hist = out + (size_t)t * NH;
        float* gtmp = (t == 2) ? wsH : hist;   // GRU output must not alias Bbuf (X) or hin (Hs)
        float* rel_t = relout + (size_t)t * R2 * H;
        const float* hprev = (t == 0) ? emb_rel : relout + (size_t)(t - 1) * R2 * H;
        const float* cprev = (t == 0) ? xin : c0b;
        const float* php   = (t == 0) ? p_rel : p_h;
        const float* pcp   = (t == 0) ? sxin : p_c;

        // ---- x_input = seg_mean(h[r_to_e], r_seg, R2) via segment CSR ----
        hipMemsetAsync(rcnt, 0, (size_t)R2 * 4, stream);
        seg_cnt_k<<<64, 256, 0, stream>>>(rseg_t, R2E, rcnt, R2);
        scan_k<<<1, 1024, 0, stream>>>(rcnt, rcsr, rcur, R2);
        seg_scatter_k<<<(R2E + 255) / 256, 256, 0, stream>>>(rseg_t, rte_t, rcur, rper, R2E);
        seg_mean_csr_k<<<R2, 256, 0, stream>>>(hin, rper, rcsr, xin, R2);
        // ---- LSTM1 ----
        lstm_k<<<R2, 256, 0, stream>>>(emb_rel, xin, hprev, cprev, Wih1, Whh1, bih1, bhh1, h0a, c0b, R2);
        // ---- sx = seg_mean(h_0[s_r_to_e], s_r_seg, SR) ----
        hipMemsetAsync(sxin, 0, (size_t)SR * H * 4, stream);
        hipMemsetAsync(scnt, 0, (size_t)SR * 4, stream);
        seg_cnt_k<<<8, 256, 0, stream>>>(srseg_t, S2E, scnt, SR);
        seg_acc_k<<<16 * 8, 256, 0, stream>>>(h0a, srte_t, srseg_t, S2E, sxin, SR);
        seg_div_k<<<(SR * H + 255) / 256, 256, 0, stream>>>(sxin, scnt, SR);
        // ---- LSTM2 ----
        lstm_k<<<SR, 256, 0, stream>>>(p_rel, sxin, php, pcp, Wih2, Whh2, bih2, bhh2, p_h, p_c, SR);
        // ---- super RGCN (2 layers) ----
        hipMemsetAsync(sindeg, 0, (size_t)R2 * 4, stream);
        cnt_k<<<(SE_EDGES + 255) / 256, 256, 0, stream>>>(sdst_t, SE_EDGES, sindeg);
        hipMemsetAsync(sagg, 0, (size_t)R2 * H * 4, stream);
        sup_agg_k<<<SE_EDGES, 256, 0, stream>>>(h0a, p_h, ssrc_t, sdst_t, set_t, sagg, SE_EDGES);
        sup_comb_k<<<R2, 256, 0, stream>>>(sagg, h0a, sWn, sWe, sWl, sindeg, srelA);
        hipMemsetAsync(sagg, 0, (size_t)R2 * H * 4, stream);
        sup_agg_k<<<SE_EDGES, 256, 0, stream>>>(srelA, p_h, ssrc_t, sdst_t, set_t, sagg, SE_EDGES);
        sup_comb_k<<<R2, 256, 0, stream>>>(sagg, srelA, sWn + H * H, sWe + H * H, sWl + H * H, sindeg, srelB);
        l2norm_k<<<(R2 + 3) / 4, 256, 0, stream>>>(srelB, srelB, R2);
        // ---- rel GRU -> rel_embs[t] ----
        gru_small_k<<<R2, 256, 0, stream>>>(srelB, h0a, Wih3, Whh3, bih3, bhh3, rel_t, R2);

        // ---- entity CSR build ----
        hipMemsetAsync(ecnt, 0, (size_t)N_NODES * 4, stream);
        hipMemsetAsync(nz, 0, 4, stream);
        cnt_k<<<(E_EDGES + 255) / 256, 256, 0, stream>>>(dst_t, E_EDGES, ecnt);
        scan_k<<<1, 1024, 0, stream>>>(ecnt, eoff, ecur, N_NODES);
        scatter_k<<<(E_EDGES + 255) / 256, 256, 0, stream>>>(dst_t, src_t, et_t, ecur, esrcp, eetp, E_EDGES);
        zlist_k<<<(N_NODES + 255) / 256, 256, 0, stream>>>(ecnt, zl, nz, N_NODES);

        dim3 gl((H + GBN - 1) / GBN, (N_NODES + GBM - 1) / GBM);  // x = N-blocks (fast)
        // ---- entity layer 0 ----
        ent_agg_k<<<(N_NODES + 3) / 4, 256, 0, stream>>>(hin, rel_t, eoff, esrcp, eetp, wsX, N_NODES);
        gemm_bf16_k<0, 1, 1><<<gl, 256, 0, stream>>>(wsX, hin, Wn, We, Abuf, N_NODES, H);
        fixup_k<<<2048, 256, 0, stream>>>(hin, Wl, zl, nz, Abuf);
        // ---- entity layer 1 ----
        ent_agg_k<<<(N_NODES + 3) / 4, 256, 0, stream>>>(Abuf, rel_t, eoff, esrcp, eetp, wsX, N_NODES);
        gemm_bf16_k<0, 1, 1><<<gl, 256, 0, stream>>>(wsX, Abuf, Wn + H * H, We + H * H, Bbuf, N_NODES, H);
        fixup_k<<<2048, 256, 0, stream>>>(Abuf, Wl + H * H, zl, nz, Bbuf);
        l2norm_k<<<(N_NODES + 3) / 4, 256, 0, stream>>>(Bbuf, Bbuf, N_NODES);

        // ---- fully fused entity GRU + final l2norm ----
        dim3 gg(4, (N_NODES + 63) / 64);
        gru_fused_k<<<gg, 256, 0, stream>>>(Bbuf, hin, Wihe, Whhe, bihe, bhhe, gtmp, N_NODES);
        l2norm_k<<<(N_NODES + 3) / 4, 256, 0, stream>>>(gtmp, hist, N_NODES);
    }
}

// Round 4
// 4249.887 us; speedup vs baseline: 2.4429x; 1.4471x over previous
//
#include <hip/hip_runtime.h>
#include <math.h>

#define N_NODES 100000
#define H 200
#define R2 500
#define T_STEPS 3
#define E_EDGES 300000
#define R2E 400000
#define SE_EDGES 4000
#define SR 8
#define S2E 8000
#define SLOPE 0.22916666666666666f

typedef unsigned short u16;
typedef unsigned int u32;
typedef __bf16 bf8 __attribute__((ext_vector_type(8)));
typedef float f32x4 __attribute__((ext_vector_type(4)));

static __device__ __forceinline__ float sigf(float x) { return 1.f / (1.f + expf(-x)); }
static __device__ __forceinline__ float bf2f(u32 lo16) {
    u32 v = lo16 << 16; float f; __builtin_memcpy(&f, &v, 4); return f;
}
static __device__ __forceinline__ u16 f2bf(float a) {
    __bf16 x = (__bf16)a; u16 u; __builtin_memcpy(&u, &x, 2); return u;
}
static __device__ __forceinline__ u32 pk2(float a, float b) {
    return (u32)f2bf(a) | ((u32)f2bf(b) << 16);
}
// bijective XCD swizzle (m204): consecutive logical ids stay on one XCD
static __device__ __forceinline__ int xcd_swz(int b, int nwg) {
    int q = nwg >> 3, r = nwg & 7;
    int xcd = b & 7, u = b >> 3;
    int start = xcd * q + (xcd < r ? xcd : r);
    return start + u;
}

// ---------------- l2 normalize rows fp32 (+optional bf16 mirror); src may alias dst ----------------
__global__ __launch_bounds__(256) void l2norm_k(const float* __restrict__ src, float* __restrict__ dst,
                                                u16* __restrict__ mir, int rows) {
    int wave = threadIdx.x >> 6, lane = threadIdx.x & 63;
    int r = blockIdx.x * 4 + wave;
    if (r >= rows) return;
    float4 v = make_float4(0.f, 0.f, 0.f, 0.f);
    if (lane < 50) v = *(const float4*)(src + (size_t)r * H + lane * 4);
    float s = v.x * v.x + v.y * v.y + v.z * v.z + v.w * v.w;
    for (int o = 32; o > 0; o >>= 1) s += __shfl_down(s, o);
    float rn = 1.f / fmaxf(sqrtf(__shfl(s, 0)), 1e-12f);
    if (lane < 50) {
        float4 o4 = make_float4(v.x * rn, v.y * rn, v.z * rn, v.w * rn);
        *(float4*)(dst + (size_t)r * H + lane * 4) = o4;
        if (mir) {
            uint2 u; u.x = pk2(o4.x, o4.y); u.y = pk2(o4.z, o4.w);
            *(uint2*)(mir + (size_t)r * H + lane * 4) = u;
        }
    }
}

// ---------------- l2 normalize bf16 rows in place ----------------
__global__ __launch_bounds__(256) void l2norm_b_k(u16* __restrict__ buf, int rows) {
    int wave = threadIdx.x >> 6, lane = threadIdx.x & 63;
    int r = blockIdx.x * 4 + wave;
    if (r >= rows) return;
    uint2 u = make_uint2(0, 0);
    if (lane < 50) u = *(const uint2*)(buf + (size_t)r * H + lane * 4);
    float x0 = bf2f(u.x & 0xffff), x1 = bf2f(u.x >> 16);
    float x2 = bf2f(u.y & 0xffff), x3 = bf2f(u.y >> 16);
    float s = x0 * x0 + x1 * x1 + x2 * x2 + x3 * x3;
    for (int o = 32; o > 0; o >>= 1) s += __shfl_down(s, o);
    float rn = 1.f / fmaxf(sqrtf(__shfl(s, 0)), 1e-12f);
    if (lane < 50) {
        uint2 o2; o2.x = pk2(x0 * rn, x1 * rn); o2.y = pk2(x2 * rn, x3 * rn);
        *(uint2*)(buf + (size_t)r * H + lane * 4) = o2;
    }
}

// ---------------- weight convert: [200][200] k-major fp32 -> [n][k] bf16 ----------------
__global__ void wconv_tr_k(const float* __restrict__ W, u16* __restrict__ o) {
    int i = blockIdx.x * 256 + threadIdx.x;
    if (i < 40000) { int n = i / 200, k = i - n * 200; o[i] = f2bf(W[k * 200 + n]); }
}
__global__ void wconv_k(const float* __restrict__ W, u16* __restrict__ o, int n) {
    int i = blockIdx.x * 256 + threadIdx.x;
    if (i < n) o[i] = f2bf(W[i]);
}

// ---------------- generic counting ----------------
__global__ void cnt_k(const int* __restrict__ d, int n, int* __restrict__ cnt) {
    int i = blockIdx.x * blockDim.x + threadIdx.x;
    if (i < n) atomicAdd(&cnt[d[i]], 1);
}

// ---------------- segment counts with LDS hierarchy ----------------
__global__ __launch_bounds__(256) void seg_cnt_k(const int* __restrict__ seg, int n,
                                                 int* __restrict__ cnt, int nseg) {
    __shared__ int lc[500];
    for (int i = threadIdx.x; i < nseg; i += 256) lc[i] = 0;
    __syncthreads();
    int chunk = (n + gridDim.x - 1) / gridDim.x;
    int beg = blockIdx.x * chunk;
    int end = beg + chunk; if (end > n) end = n;
    for (int i = beg + threadIdx.x; i < end; i += 256) atomicAdd(&lc[seg[i]], 1);
    __syncthreads();
    for (int i = threadIdx.x; i < nseg; i += 256) if (lc[i]) atomicAdd(&cnt[i], lc[i]);
}

// ---------------- small segment sum (SR path), LDS col-chunked ----------------
#define SEG_CW 25
__global__ __launch_bounds__(256) void seg_acc_k(const float* __restrict__ hsrc,
                                                 const int* __restrict__ idx,
                                                 const int* __restrict__ seg, int n,
                                                 float* __restrict__ acc, int nseg) {
    __shared__ float lacc[500 * SEG_CW];
    int cg = blockIdx.x & 7;
    int pb = blockIdx.x >> 3;
    int NPB = gridDim.x >> 3;
    int t = threadIdx.x;
    for (int i = t; i < nseg * SEG_CW; i += 256) lacc[i] = 0.f;
    __syncthreads();
    int chunk = (n + NPB - 1) / NPB;
    int beg = pb * chunk;
    int end = beg + chunk; if (end > n) end = n;
    if (t < 250) {
        int il = t / SEG_CW;
        int c = t - il * SEG_CW;
        int col = cg * SEG_CW + c;
        for (int i = beg + il; i < end; i += 10) {
            int r = seg[i];
            int e = idx[i];
            atomicAdd(&lacc[r * SEG_CW + c], hsrc[(size_t)e * H + col]);
        }
    }
    __syncthreads();
    for (int i = t; i < nseg * SEG_CW; i += 256) {
        int r = i / SEG_CW, c = i - (i / SEG_CW) * SEG_CW;
        atomicAdd(&acc[(size_t)r * H + cg * SEG_CW + c], lacc[i]);
    }
}

__global__ void seg_div_k(float* __restrict__ acc, const int* __restrict__ cnt, int rows) {
    int i = blockIdx.x * blockDim.x + threadIdx.x;
    if (i < rows * H) {
        int c = cnt[i / H];
        acc[i] /= (float)(c > 0 ? c : 1);
    }
}

// ---------------- segment permutation scatter ----------------
__global__ void seg_scatter_k(const int* __restrict__ seg, const int* __restrict__ val,
                              int* __restrict__ cur, int* __restrict__ outp, int n) {
    int i = blockIdx.x * blockDim.x + threadIdx.x;
    if (i < n) {
        int p = atomicAdd(&cur[seg[i]], 1);
        outp[p] = val[i];
    }
}

// ---------------- CSR segment mean over bf16 rows ----------------
__global__ __launch_bounds__(256) void seg_mean_csr_b_k(const u16* __restrict__ h,
                                                        const int* __restrict__ per,
                                                        const int* __restrict__ off,
                                                        float* __restrict__ xout, int nseg) {
    int r = blockIdx.x;
    if (r >= nseg) return;
    int t = threadIdx.x;
    int beg = off[r], end = off[r + 1];
    if (t >= H) return;
    float acc = 0.f;
    int i = beg;
    for (; i + 4 <= end; i += 4) {
        int e0 = per[i], e1 = per[i + 1], e2 = per[i + 2], e3 = per[i + 3];
        acc += bf2f(h[(size_t)e0 * H + t]) + bf2f(h[(size_t)e1 * H + t]) +
               bf2f(h[(size_t)e2 * H + t]) + bf2f(h[(size_t)e3 * H + t]);
    }
    for (; i < end; ++i) acc += bf2f(h[(size_t)per[i] * H + t]);
    float c = (float)(end - beg);
    xout[(size_t)r * H + t] = acc / fmaxf(c, 1.f);
}

// ---------------- fused LSTM cell + l2norm of h and c ----------------
__global__ __launch_bounds__(256) void lstm_k(const float* __restrict__ x1, const float* __restrict__ x2,
                                              const float* __restrict__ hprev, const float* __restrict__ cprev,
                                              const float* __restrict__ Wih, const float* __restrict__ Whh,
                                              const float* __restrict__ bih, const float* __restrict__ bhh,
                                              float* __restrict__ hout, float* __restrict__ cout, int rows) {
    int r = blockIdx.x;
    if (r >= rows) return;
    __shared__ float xb[2 * H], hb[H], gb[4 * H], hv[H], cv[H];
    __shared__ float red[8];
    int t = threadIdx.x;
    for (int i = t; i < 2 * H; i += 256)
        xb[i] = (i < H) ? x1[(size_t)r * H + i] : x2[(size_t)r * H + i - H];
    if (t < H) hb[t] = hprev[(size_t)r * H + t];
    __syncthreads();
    for (int j = t; j < 4 * H; j += 256) {
        float s = bih[j] + bhh[j];
        const float* wi = Wih + (size_t)j * 2 * H;
        for (int k = 0; k < 2 * H; ++k) s += xb[k] * wi[k];
        const float* wh = Whh + (size_t)j * H;
        for (int k = 0; k < H; ++k) s += hb[k] * wh[k];
        gb[j] = s;
    }
    __syncthreads();
    if (t < H) {
        float ig = sigf(gb[t]);
        float fg = sigf(gb[H + t]);
        float gg = tanhf(gb[2 * H + t]);
        float og = sigf(gb[3 * H + t]);
        float c2 = fg * cprev[(size_t)r * H + t] + ig * gg;
        cv[t] = c2;
        hv[t] = og * tanhf(c2);
    }
    __syncthreads();
    float sh = 0.f, sc = 0.f;
    if (t < H) { sh = hv[t] * hv[t]; sc = cv[t] * cv[t]; }
    for (int o = 32; o > 0; o >>= 1) { sh += __shfl_down(sh, o); sc += __shfl_down(sc, o); }
    if ((t & 63) == 0) { red[t >> 6] = sh; red[4 + (t >> 6)] = sc; }
    __syncthreads();
    if (t == 0) {
        red[0] = 1.f / fmaxf(sqrtf(red[0] + red[1] + red[2] + red[3]), 1e-12f);
        red[4] = 1.f / fmaxf(sqrtf(red[4] + red[5] + red[6] + red[7]), 1e-12f);
    }
    __syncthreads();
    if (t < H) {
        hout[(size_t)r * H + t] = hv[t] * red[0];
        cout[(size_t)r * H + t] = cv[t] * red[4];
    }
}

// ---------------- fused small GRU + l2norm (+bf16 mirror) ----------------
__global__ __launch_bounds__(256) void gru_small_k(const float* __restrict__ x, const float* __restrict__ h,
                                                   const float* __restrict__ Wih, const float* __restrict__ Whh,
                                                   const float* __restrict__ bih, const float* __restrict__ bhh,
                                                   float* __restrict__ outp, u16* __restrict__ mirp, int rows) {
    int r = blockIdx.x;
    if (r >= rows) return;
    __shared__ float xb[H], hb[H], gi[3 * H], gh[3 * H], ov[H];
    __shared__ float red[4];
    int t = threadIdx.x;
    if (t < H) { xb[t] = x[(size_t)r * H + t]; hb[t] = h[(size_t)r * H + t]; }
    __syncthreads();
    for (int j = t; j < 3 * H; j += 256) {
        float si = bih[j], sh2 = bhh[j];
        const float* wi = Wih + (size_t)j * H;
        const float* wh = Whh + (size_t)j * H;
        for (int k = 0; k < H; ++k) { si += xb[k] * wi[k]; sh2 += hb[k] * wh[k]; }
        gi[j] = si; gh[j] = sh2;
    }
    __syncthreads();
    if (t < H) {
        float rr = sigf(gi[t] + gh[t]);
        float zz = sigf(gi[H + t] + gh[H + t]);
        float nn = tanhf(gi[2 * H + t] + rr * gh[2 * H + t]);
        ov[t] = (1.f - zz) * nn + zz * hb[t];
    }
    __syncthreads();
    float s = (t < H) ? ov[t] * ov[t] : 0.f;
    for (int o = 32; o > 0; o >>= 1) s += __shfl_down(s, o);
    if ((t & 63) == 0) red[t >> 6] = s;
    __syncthreads();
    if (t == 0) red[0] = 1.f / fmaxf(sqrtf(red[0] + red[1] + red[2] + red[3]), 1e-12f);
    __syncthreads();
    if (t < H) {
        float v = ov[t] * red[0];
        outp[(size_t)r * H + t] = v;
        mirp[(size_t)r * H + t] = f2bf(v);
    }
}

// ---------------- super-graph raw message aggregation (fp32) ----------------
__global__ __launch_bounds__(256) void sup_agg_k(const float* __restrict__ cur, const float* __restrict__ prel,
                                                 const int* __restrict__ ss, const int* __restrict__ sd,
                                                 const int* __restrict__ se, float* __restrict__ sagg, int nE) {
    int e = blockIdx.x;
    if (e >= nE) return;
    int t = threadIdx.x;
    if (t < H) {
        int s = ss[e], d = sd[e], et = se[e];
        float v = cur[(size_t)s * H + t] + prel[(size_t)et * H + t];
        atomicAdd(&sagg[(size_t)d * H + t], v);
    }
}

// ---------------- super-graph combine: rrelu(agg@Wn + cur@Wsel) ----------------
__global__ __launch_bounds__(256) void sup_comb_k(const float* __restrict__ agg, const float* __restrict__ cur,
                                                  const float* __restrict__ Wn, const float* __restrict__ We,
                                                  const float* __restrict__ Wl, const int* __restrict__ indeg,
                                                  float* __restrict__ outp) {
    int r = blockIdx.x;
    __shared__ float ar[H], cr[H];
    int t = threadIdx.x;
    if (t < H) { ar[t] = agg[(size_t)r * H + t]; cr[t] = cur[(size_t)r * H + t]; }
    __syncthreads();
    const float* W2 = (indeg[r] > 0) ? We : Wl;
    if (t < H) {
        float s = 0.f;
        for (int k = 0; k < H; ++k) s += ar[k] * Wn[(size_t)k * H + t] + cr[k] * W2[(size_t)k * H + t];
        outp[(size_t)r * H + t] = (s >= 0.f) ? s : s * SLOPE;
    }
}

// ---------------- CSR scan (single block) ----------------
__global__ __launch_bounds__(1024) void scan_k(const int* __restrict__ cnt, int* __restrict__ off,
                                               int* __restrict__ cur, int n) {
    __shared__ int part[1024];
    int tid = threadIdx.x;
    int per = (n + 1023) / 1024;
    int s0 = tid * per;
    int e0 = s0 + per; if (e0 > n) e0 = n;
    int sum = 0;
    for (int i = s0; i < e0; ++i) sum += cnt[i];
    part[tid] = sum;
    __syncthreads();
    for (int d = 1; d < 1024; d <<= 1) {
        int v = (tid >= d) ? part[tid - d] : 0;
        __syncthreads();
        part[tid] += v;
        __syncthreads();
    }
    int excl = (tid == 0) ? 0 : part[tid - 1];
    for (int i = s0; i < e0; ++i) { off[i] = excl; cur[i] = excl; excl += cnt[i]; }
    if (tid == 1023) off[n] = excl;
}

__global__ void scatter_k(const int* __restrict__ dst, const int* __restrict__ src,
                          const int* __restrict__ et, int* __restrict__ cur,
                          int* __restrict__ psrc, int* __restrict__ pet, int nE) {
    int e = blockIdx.x * blockDim.x + threadIdx.x;
    if (e < nE) {
        int p = atomicAdd(&cur[dst[e]], 1);
        psrc[p] = src[e];
        pet[p] = et[e];
    }
}

__global__ void zlist_k(const int* __restrict__ cnt, int* __restrict__ zl, int* __restrict__ nz, int n) {
    int v = blockIdx.x * blockDim.x + threadIdx.x;
    if (v < n && cnt[v] == 0) {
        int p = atomicAdd(nz, 1);
        zl[p] = v;
    }
}

// ---------------- entity message aggregation via CSR, bf16 in / bf16 out ----------------
__global__ __launch_bounds__(256) void ent_agg_b_k(const u16* __restrict__ cur, const u16* __restrict__ rel,
                                                   const int* __restrict__ eoff, const int* __restrict__ esrc,
                                                   const int* __restrict__ eet, u16* __restrict__ agg, int n) {
    int wave = threadIdx.x >> 6, lane = threadIdx.x & 63;
    int v = blockIdx.x * 4 + wave;
    if (v >= n) return;
    float a0 = 0.f, a1 = 0.f, a2 = 0.f, a3 = 0.f;
    bool lo36 = lane < 36;
    int beg = eoff[v], end = eoff[v + 1];
    for (int i = beg; i < end; ++i) {
        const u32* hr = (const u32*)(cur + (size_t)esrc[i] * H);
        const u32* rr = (const u32*)(rel + (size_t)eet[i] * H);
        u32 h0 = hr[lane], r0 = rr[lane];
        a0 += bf2f(h0 & 0xffff) + bf2f(r0 & 0xffff);
        a1 += bf2f(h0 >> 16) + bf2f(r0 >> 16);
        if (lo36) {
            u32 h1 = hr[64 + lane], r1 = rr[64 + lane];
            a2 += bf2f(h1 & 0xffff) + bf2f(r1 & 0xffff);
            a3 += bf2f(h1 >> 16) + bf2f(r1 >> 16);
        }
    }
    u32* o = (u32*)(agg + (size_t)v * H);
    o[lane] = pk2(a0, a1);
    if (lo36) o[64 + lane] = pk2(a2, a3);
}

// ---------------- bf16 MFMA GEMM, all-bf16 operands, rrelu, bf16 out ----------------
// Cm[M][Nc] = rrelu(A1@B1^T + A2@B2^T), A row-major [M][200] bf16, B [Nc][200] bf16
#define GBM 128
#define GBN 64
#define LDT 40

__global__ __launch_bounds__(256, 4) void gemm_bb_k(const u16* __restrict__ A1, const u16* __restrict__ A2,
                                                    const u16* __restrict__ B1, const u16* __restrict__ B2,
                                                    u16* __restrict__ Cm, int M, int Nc) {
    __shared__ __bf16 Asm[GBM * LDT];
    __shared__ __bf16 Bsm[GBN * LDT];
    const int tid = threadIdx.x;
    int idx2 = xcd_swz(blockIdx.x, gridDim.x);
    const int m0 = (idx2 >> 2) * GBM;
    const int n0 = (idx2 & 3) * GBN;
    const int w = tid >> 6, lane = tid & 63;
    const int wr = w >> 1, wc = w & 1;
    const int lr = lane & 15, lo = lane >> 4;
    f32x4 acc[4][2];
#pragma unroll
    for (int i = 0; i < 4; ++i)
#pragma unroll
        for (int j = 0; j < 2; ++j)
#pragma unroll
            for (int e = 0; e < 4; ++e) acc[i][j][e] = 0.f;

    for (int kt = 0; kt < 14; ++kt) {
        const u16* Ap = (kt >= 7) ? A2 : A1;
        const u16* Bp = (kt >= 7) ? B2 : B1;
        const int k0 = (kt >= 7 ? kt - 7 : kt) * 32;
        if (kt) __syncthreads();
#pragma unroll
        for (int i = 0; i < 2; ++i) {
            int ch = tid + i * 256;
            int row = ch >> 2, q = ch & 3;
            int m = m0 + row, k = k0 + q * 8;
            uint4 v = make_uint4(0, 0, 0, 0);
            if (m < M && k < 200) v = *(const uint4*)(Ap + (size_t)m * 200 + k);
            *(uint4*)(&Asm[row * LDT + q * 8]) = v;
        }
        {
            int row = tid >> 2, q = tid & 3;
            int n = n0 + row, k = k0 + q * 8;
            uint4 v = make_uint4(0, 0, 0, 0);
            if (n < Nc && k < 200) v = *(const uint4*)(Bp + (size_t)n * 200 + k);
            *(uint4*)(&Bsm[row * LDT + q * 8]) = v;
        }
        __syncthreads();
        bf8 af[4], bfr[2];
#pragma unroll
        for (int mf = 0; mf < 4; ++mf)
            af[mf] = *(const bf8*)(&Asm[(wr * 64 + mf * 16 + lr) * LDT + lo * 8]);
#pragma unroll
        for (int nf = 0; nf < 2; ++nf)
            bfr[nf] = *(const bf8*)(&Bsm[(wc * 32 + nf * 16 + lr) * LDT + lo * 8]);
#pragma unroll
        for (int mf = 0; mf < 4; ++mf)
#pragma unroll
            for (int nf = 0; nf < 2; ++nf)
                acc[mf][nf] = __builtin_amdgcn_mfma_f32_16x16x32_bf16(af[mf], bfr[nf], acc[mf][nf], 0, 0, 0);
    }
#pragma unroll
    for (int mf = 0; mf < 4; ++mf) {
#pragma unroll
        for (int r = 0; r < 4; ++r) {
            int m = m0 + wr * 64 + mf * 16 + lo * 4 + r;
            if (m >= M) continue;
#pragma unroll
            for (int nf = 0; nf < 2; ++nf) {
                int n = n0 + wc * 32 + nf * 16 + lr;
                if (n >= Nc) continue;
                float v = acc[mf][nf][r];
                v = (v >= 0.f) ? v : v * SLOPE;
                Cm[(size_t)m * Nc + n] = f2bf(v);
            }
        }
    }
}

// ---------------- fixup for zero-indeg rows: out[row] = rrelu(h[row] @ Wl), bf16 io ----------------
__global__ __launch_bounds__(256) void fixup_b_k(const u16* __restrict__ h, const float* __restrict__ Wl,
                                                 const int* __restrict__ zl, const int* __restrict__ nz,
                                                 u16* __restrict__ outp) {
    __shared__ float xr[H];
    int nzv = *nz;
    for (int z = blockIdx.x; z < nzv; z += gridDim.x) {
        int row = zl[z];
        if (threadIdx.x < H) xr[threadIdx.x] = bf2f(h[(size_t)row * H + threadIdx.x]);
        __syncthreads();
        if (threadIdx.x < H) {
            float s = 0.f;
            for (int k = 0; k < H; ++k) s += xr[k] * Wl[(size_t)k * H + threadIdx.x];
            outp[(size_t)row * H + threadIdx.x] = f2bf((s >= 0.f) ? s : s * SLOPE);
        }
        __syncthreads();
    }
}

// ---------------- fully fused entity GRU, bf16 operands staged from global bf16 ----------------
// Wb: [1200][200] bf16 = Wihe rows 0..599 then Whhe rows 600..1199
__global__ __launch_bounds__(256, 2) void gru_fused_k(const u16* __restrict__ Xb, const u16* __restrict__ Hb,
                                                      const float* __restrict__ Hf, const u16* __restrict__ Wb,
                                                      const float* __restrict__ bih, const float* __restrict__ bhh,
                                                      float* __restrict__ Out, int M) {
    __shared__ __bf16 Xs[64 * LDT];
    __shared__ __bf16 Hs[64 * LDT];
    __shared__ __bf16 Ws[6][64 * LDT];
    const int tid = threadIdx.x;
    int idx2 = xcd_swz(blockIdx.x, gridDim.x);
    const int m0 = (idx2 >> 2) * 64;
    const int n0 = (idx2 & 3) * 64;
    const int w = tid >> 6, lane = tid & 63;
    const int wr = w >> 1, wc = w & 1;
    const int lr = lane & 15, lo = lane >> 4;
    const int row = tid >> 2, q = tid & 3;
    f32x4 acc[6][2][2];
#pragma unroll
    for (int s = 0; s < 6; ++s)
#pragma unroll
        for (int i = 0; i < 2; ++i)
#pragma unroll
            for (int j = 0; j < 2; ++j)
#pragma unroll
                for (int e = 0; e < 4; ++e) acc[s][i][j][e] = 0.f;

    for (int kt = 0; kt < 7; ++kt) {
        const int k = kt * 32 + q * 8;
        const bool kv = k < 200;
        if (kt) __syncthreads();
        {
            int m = m0 + row;
            uint4 vx = make_uint4(0, 0, 0, 0), vh = make_uint4(0, 0, 0, 0);
            if (m < M && kv) {
                vx = *(const uint4*)(Xb + (size_t)m * 200 + k);
                vh = *(const uint4*)(Hb + (size_t)m * 200 + k);
            }
            *(uint4*)(&Xs[row * LDT + q * 8]) = vx;
            *(uint4*)(&Hs[row * LDT + q * 8]) = vh;
        }
        {
            int c = n0 + row;
#pragma unroll
            for (int s = 0; s < 6; ++s) {
                uint4 v = make_uint4(0, 0, 0, 0);
                if (c < 200 && kv) v = *(const uint4*)(Wb + (size_t)(s * 200 + c) * 200 + k);
                *(uint4*)(&Ws[s][row * LDT + q * 8]) = v;
            }
        }
        __syncthreads();
        bf8 xa[2], ha[2];
#pragma unroll
        for (int mf = 0; mf < 2; ++mf) {
            xa[mf] = *(const bf8*)(&Xs[(wr * 32 + mf * 16 + lr) * LDT + lo * 8]);
            ha[mf] = *(const bf8*)(&Hs[(wr * 32 + mf * 16 + lr) * LDT + lo * 8]);
        }
#pragma unroll
        for (int s = 0; s < 6; ++s) {
            bf8 w0 = *(const bf8*)(&Ws[s][(wc * 32 + lr) * LDT + lo * 8]);
            bf8 w1 = *(const bf8*)(&Ws[s][(wc * 32 + 16 + lr) * LDT + lo * 8]);
#pragma unroll
            for (int mf = 0; mf < 2; ++mf) {
                bf8 a = (s < 3) ? xa[mf] : ha[mf];
                acc[s][mf][0] = __builtin_amdgcn_mfma_f32_16x16x32_bf16(a, w0, acc[s][mf][0], 0, 0, 0);
                acc[s][mf][1] = __builtin_amdgcn_mfma_f32_16x16x32_bf16(a, w1, acc[s][mf][1], 0, 0, 0);
            }
        }
    }
    // epilogue: GRU nonlinearity; fp32 h master for the z*h term
#pragma unroll
    for (int nf = 0; nf < 2; ++nf) {
        int c = n0 + wc * 32 + nf * 16 + lr;
        if (c >= 200) continue;
        float b0 = bih[c], b1 = bih[200 + c], b2 = bih[400 + c];
        float b3 = bhh[c], b4 = bhh[200 + c], b5 = bhh[400 + c];
#pragma unroll
        for (int mf = 0; mf < 2; ++mf) {
#pragma unroll
            for (int r = 0; r < 4; ++r) {
                int m = m0 + wr * 32 + mf * 16 + lo * 4 + r;
                if (m >= M) continue;
                float ir = acc[0][mf][nf][r] + b0;
                float iz = acc[1][mf][nf][r] + b1;
                float in_ = acc[2][mf][nf][r] + b2;
                float hr = acc[3][mf][nf][r] + b3;
                float hz = acc[4][mf][nf][r] + b4;
                float hn = acc[5][mf][nf][r] + b5;
                float rr = sigf(ir + hr);
                float zz = sigf(iz + hz);
                float nn = tanhf(in_ + rr * hn);
                Out[(size_t)m * H + c] = (1.f - zz) * nn + zz * Hf[(size_t)m * H + c];
            }
        }
    }
}

// =========================== host orchestration ===========================
extern "C" void kernel_launch(void* const* d_in, const int* in_sizes, int n_in,
                              void* d_out, int out_size, void* d_ws, size_t ws_size,
                              hipStream_t stream) {
    (void)in_sizes; (void)n_in; (void)out_size; (void)ws_size;
    const int* src  = (const int*)d_in[0];
    const int* dst  = (const int*)d_in[1];
    const int* etyp = (const int*)d_in[2];
    const int* rte  = (const int*)d_in[3];
    const int* rseg = (const int*)d_in[4];
    const int* ssrc = (const int*)d_in[5];
    const int* sdst = (const int*)d_in[6];
    const int* setp = (const int*)d_in[7];
    const int* srte = (const int*)d_in[8];
    const int* srseg= (const int*)d_in[9];
    const float* dyn     = (const float*)d_in[10];
    const float* emb_rel = (const float*)d_in[11];
    const float* p_rel   = (const float*)d_in[12];
    const float* Wih1 = (const float*)d_in[13]; const float* Whh1 = (const float*)d_in[14];
    const float* bih1 = (const float*)d_in[15]; const float* bhh1 = (const float*)d_in[16];
    const float* Wih2 = (const float*)d_in[17]; const float* Whh2 = (const float*)d_in[18];
    const float* bih2 = (const float*)d_in[19]; const float* bhh2 = (const float*)d_in[20];
    const float* Wih3 = (const float*)d_in[21]; const float* Whh3 = (const float*)d_in[22];
    const float* bih3 = (const float*)d_in[23]; const float* bhh3 = (const float*)d_in[24];
    const float* Wihe = (const float*)d_in[25]; const float* Whhe = (const float*)d_in[26];
    const float* bihe = (const float*)d_in[27]; const float* bhhe = (const float*)d_in[28];
    const float* Wn  = (const float*)d_in[29];
    const float* Wl  = (const float*)d_in[30];
    const float* We  = (const float*)d_in[31];
    const float* sWn = (const float*)d_in[32];
    const float* sWl = (const float*)d_in[33];
    const float* sWe = (const float*)d_in[34];

    float* out = (float*)d_out;
    const size_t NH = (size_t)N_NODES * H;
    float* relout = out + 3 * NH;

    char* wp = (char*)d_ws;
    auto carve = [&](size_t bytes) -> void* {
        void* p = (void*)wp;
        wp += (bytes + 255) & ~(size_t)255;
        return p;
    };
    u16* aggB = (u16*)carve(NH * 2);
    u16* m0b  = (u16*)carve(NH * 2);
    u16* m1b  = (u16*)carve(NH * 2);
    u16* hmir = (u16*)carve(NH * 2);
    u16* relm = (u16*)carve((size_t)R2 * H * 2);
    u16* wtB  = (u16*)carve((size_t)400000 * 2);
    float* h0a  = (float*)carve((size_t)R2 * H * 4);
    float* c0b  = (float*)carve((size_t)R2 * H * 4);
    float* xin  = (float*)carve((size_t)R2 * H * 4);
    float* srelA= (float*)carve((size_t)R2 * H * 4);
    float* srelB= (float*)carve((size_t)R2 * H * 4);
    float* sagg = (float*)carve((size_t)R2 * H * 4);
    float* sxin = (float*)carve((size_t)SR * H * 4);
    float* p_h  = (float*)carve((size_t)SR * H * 4);
    float* p_c  = (float*)carve((size_t)SR * H * 4);
    int* ecnt  = (int*)carve((size_t)N_NODES * 4);
    int* eoff  = (int*)carve((size_t)(N_NODES + 1) * 4);
    int* ecur  = (int*)carve((size_t)N_NODES * 4);
    int* esrcp = (int*)carve((size_t)E_EDGES * 4);
    int* eetp  = (int*)carve((size_t)E_EDGES * 4);
    int* zl    = (int*)carve((size_t)N_NODES * 4);
    int* nz    = (int*)carve(4);
    int* rcnt  = (int*)carve((size_t)R2 * 4);
    int* scnt  = (int*)carve((size_t)SR * 4);
    int* sindeg= (int*)carve((size_t)R2 * 4);
    int* rper  = (int*)carve((size_t)R2E * 4);
    int* rcsr  = (int*)carve((size_t)(R2 + 1) * 4);
    int* rcur  = (int*)carve((size_t)R2 * 4);

    // ---- weights -> bf16 (transposed for GEMM B-operand) ----
    wconv_tr_k<<<157, 256, 0, stream>>>(Wn,          wtB);
    wconv_tr_k<<<157, 256, 0, stream>>>(We,          wtB + 40000);
    wconv_tr_k<<<157, 256, 0, stream>>>(Wn + 40000,  wtB + 80000);
    wconv_tr_k<<<157, 256, 0, stream>>>(We + 40000,  wtB + 120000);
    wconv_k<<<469, 256, 0, stream>>>(Wihe, wtB + 160000, 120000);
    wconv_k<<<469, 256, 0, stream>>>(Whhe, wtB + 280000, 120000);

    // h = l2norm(dynamic_emb) -> out+NH (fp32 master, t=0) + hmir
    l2norm_k<<<(N_NODES + 3) / 4, 256, 0, stream>>>(dyn, out + NH, hmir, N_NODES);

    const int gw  = 4 * ((N_NODES + GBM - 1) / GBM);  // 3128
    const int gwg = 4 * ((N_NODES + 63) / 64);        // 6252

    for (int t = 0; t < T_STEPS; ++t) {
        const int* src_t  = src + (size_t)t * E_EDGES;
        const int* dst_t  = dst + (size_t)t * E_EDGES;
        const int* et_t   = etyp + (size_t)t * E_EDGES;
        const int* rte_t  = rte + (size_t)t * R2E;
        const int* rseg_t = rseg + (size_t)t * R2E;
        const int* ssrc_t = ssrc + (size_t)t * SE_EDGES;
        const int* sdst_t = sdst + (size_t)t * SE_EDGES;
        const int* set_t  = setp + (size_t)t * SE_EDGES;
        const int* srte_t = srte + (size_t)t * S2E;
        const int* srseg_t= srseg + (size_t)t * S2E;

        float* hin  = (t == 0) ? out + NH : out + (size_t)(t - 1) * NH;  // fp32 h master
        float* hist = out + (size_t)t * NH;
        float* rel_t = relout + (size_t)t * R2 * H;
        const float* hprev = (t == 0) ? emb_rel : relout + (size_t)(t - 1) * R2 * H;
        const float* cprev = (t == 0) ? xin : c0b;
        const float* php   = (t == 0) ? p_rel : p_h;
        const float* pcp   = (t == 0) ? sxin : p_c;

        // ---- x_input = seg_mean(h[r_to_e], r_seg, R2) via segment CSR (bf16 gather) ----
        hipMemsetAsync(rcnt, 0, (size_t)R2 * 4, stream);
        seg_cnt_k<<<64, 256, 0, stream>>>(rseg_t, R2E, rcnt, R2);
        scan_k<<<1, 1024, 0, stream>>>(rcnt, rcsr, rcur, R2);
        seg_scatter_k<<<(R2E + 255) / 256, 256, 0, stream>>>(rseg_t, rte_t, rcur, rper, R2E);
        seg_mean_csr_b_k<<<R2, 256, 0, stream>>>(hmir, rper, rcsr, xin, R2);
        // ---- LSTM1 ----
        lstm_k<<<R2, 256, 0, stream>>>(emb_rel, xin, hprev, cprev, Wih1, Whh1, bih1, bhh1, h0a, c0b, R2);
        // ---- sx = seg_mean(h_0[s_r_to_e], s_r_seg, SR) ----
        hipMemsetAsync(sxin, 0, (size_t)SR * H * 4, stream);
        hipMemsetAsync(scnt, 0, (size_t)SR * 4, stream);
        seg_cnt_k<<<8, 256, 0, stream>>>(srseg_t, S2E, scnt, SR);
        seg_acc_k<<<16 * 8, 256, 0, stream>>>(h0a, srte_t, srseg_t, S2E, sxin, SR);
        seg_div_k<<<(SR * H + 255) / 256, 256, 0, stream>>>(sxin, scnt, SR);
        // ---- LSTM2 ----
        lstm_k<<<SR, 256, 0, stream>>>(p_rel, sxin, php, pcp, Wih2, Whh2, bih2, bhh2, p_h, p_c, SR);
        // ---- super RGCN (2 layers) ----
        hipMemsetAsync(sindeg, 0, (size_t)R2 * 4, stream);
        cnt_k<<<(SE_EDGES + 255) / 256, 256, 0, stream>>>(sdst_t, SE_EDGES, sindeg);
        hipMemsetAsync(sagg, 0, (size_t)R2 * H * 4, stream);
        sup_agg_k<<<SE_EDGES, 256, 0, stream>>>(h0a, p_h, ssrc_t, sdst_t, set_t, sagg, SE_EDGES);
        sup_comb_k<<<R2, 256, 0, stream>>>(sagg, h0a, sWn, sWe, sWl, sindeg, srelA);
        hipMemsetAsync(sagg, 0, (size_t)R2 * H * 4, stream);
        sup_agg_k<<<SE_EDGES, 256, 0, stream>>>(srelA, p_h, ssrc_t, sdst_t, set_t, sagg, SE_EDGES);
        sup_comb_k<<<R2, 256, 0, stream>>>(sagg, srelA, sWn + H * H, sWe + H * H, sWl + H * H, sindeg, srelB);
        l2norm_k<<<(R2 + 3) / 4, 256, 0, stream>>>(srelB, srelB, (u16*)nullptr, R2);
        // ---- rel GRU -> rel_embs[t] (+bf16 mirror) ----
        gru_small_k<<<R2, 256, 0, stream>>>(srelB, h0a, Wih3, Whh3, bih3, bhh3, rel_t, relm, R2);

        // ---- entity CSR build ----
        hipMemsetAsync(ecnt, 0, (size_t)N_NODES * 4, stream);
        hipMemsetAsync(nz, 0, 4, stream);
        cnt_k<<<(E_EDGES + 255) / 256, 256, 0, stream>>>(dst_t, E_EDGES, ecnt);
        scan_k<<<1, 1024, 0, stream>>>(ecnt, eoff, ecur, N_NODES);
        scatter_k<<<(E_EDGES + 255) / 256, 256, 0, stream>>>(dst_t, src_t, et_t, ecur, esrcp, eetp, E_EDGES);
        zlist_k<<<(N_NODES + 255) / 256, 256, 0, stream>>>(ecnt, zl, nz, N_NODES);

        // ---- entity layer 0 (bf16 in, bf16 out) ----
        ent_agg_b_k<<<(N_NODES + 3) / 4, 256, 0, stream>>>(hmir, relm, eoff, esrcp, eetp, aggB, N_NODES);
        gemm_bb_k<<<gw, 256, 0, stream>>>(aggB, hmir, wtB, wtB + 40000, m0b, N_NODES, H);
        fixup_b_k<<<2048, 256, 0, stream>>>(hmir, Wl, zl, nz, m0b);
        // ---- entity layer 1 ----
        ent_agg_b_k<<<(N_NODES + 3) / 4, 256, 0, stream>>>(m0b, relm, eoff, esrcp, eetp, aggB, N_NODES);
        gemm_bb_k<<<gw, 256, 0, stream>>>(aggB, m0b, wtB + 80000, wtB + 120000, m1b, N_NODES, H);
        fixup_b_k<<<2048, 256, 0, stream>>>(m0b, Wl + H * H, zl, nz, m1b);
        l2norm_b_k<<<(N_NODES + 3) / 4, 256, 0, stream>>>(m1b, N_NODES);

        // ---- fused entity GRU -> hist (fp32), then in-place l2norm + hmir ----
        gru_fused_k<<<gwg, 256, 0, stream>>>(m1b, hmir, hin, wtB + 160000, bihe, bhhe, hist, N_NODES);
        l2norm_k<<<(N_NODES + 3) / 4, 256, 0, stream>>>(hist, hist, hmir, N_NODES);
    }
}